// Round 1
// 350.464 us; speedup vs baseline: 1.0450x; 1.0450x over previous
//
#include <hip/hip_runtime.h>
#include <hip/hip_bf16.h>

typedef __attribute__((ext_vector_type(8))) short bf16x8;   // 8 bf16 in 4 VGPRs
typedef __attribute__((ext_vector_type(4))) float floatx4;

#define MFMA_16x16x32(A, B, C) __builtin_amdgcn_mfma_f32_16x16x32_bf16(A, B, C, 0, 0, 0)

__device__ __forceinline__ unsigned short f2b(float f) {
    __hip_bfloat16 h = __float2bfloat16(f);  // RNE
    unsigned short u;
    __builtin_memcpy(&u, &h, 2);
    return u;
}
// pack 2 floats -> 2 bf16 (RNE) in one u32 (v_cvt_pk_bf16_f32 on gfx950)
__device__ __forceinline__ unsigned pk2(float a, float b) {
    __hip_bfloat162 h = __float22bfloat162_rn(float2{a, b});
    unsigned u;
    __builtin_memcpy(&u, &h, 4);
    return u;
}
__device__ __forceinline__ void async_lds16(const void* g, void* l) {
    __builtin_amdgcn_global_load_lds((__attribute__((address_space(1))) void*)g,
                                     (__attribute__((address_space(3))) void*)l, 16, 0, 0);
}

// ---------------- fp32 -> bf16 bulk convert (with per-tensor scale) ----------------
struct CvtArgs {
    const float* src[6];
    unsigned short* dst[6];
    float scale[6];
    int n8[6];
};
__global__ __launch_bounds__(256) void convert_kernel(CvtArgs a) {
    const int t = blockIdx.y;
    const int i = blockIdx.x * 256 + threadIdx.x;
    if (i >= a.n8[t]) return;
    const float sc = a.scale[t];
    const float4* s = (const float4*)a.src[t];
    const float4 x = s[2 * i], y = s[2 * i + 1];
    bf16x8 v;
    v[0] = (short)f2b(x.x * sc); v[1] = (short)f2b(x.y * sc);
    v[2] = (short)f2b(x.z * sc); v[3] = (short)f2b(x.w * sc);
    v[4] = (short)f2b(y.x * sc); v[5] = (short)f2b(y.y * sc);
    v[6] = (short)f2b(y.z * sc); v[7] = (short)f2b(y.w * sc);
    *(bf16x8*)(a.dst[t] + (size_t)i * 8) = v;
}

// ---------------- fused QKV projection GEMM (double-buffered, XCD-swizzled) ----------------
struct QKVArgs {
    const unsigned short* A[3];
    const unsigned short* B[3];
    const float* bias[3];
    float bscale[3];
    unsigned short* C[3];
};
__global__ __launch_bounds__(256) void gemm_qkv(QKVArgs args) {
    constexpr int M = 8192, N = 1024, K = 1024;
    __shared__ __align__(16) unsigned short As[2][4096];
    __shared__ __align__(16) unsigned short Bs[2][4096];

    const int z = blockIdx.z;
    const unsigned short* __restrict__ A = args.A[z];
    const unsigned short* __restrict__ B = args.B[z];
    const float* __restrict__ bias = args.bias[z];
    const float bsc = args.bscale[z];
    unsigned short* __restrict__ C = args.C[z];

    const int tid  = threadIdx.x;
    const int wave = tid >> 6;
    const int lane = tid & 63;
    const int l16  = lane & 15;
    const int quad = lane >> 4;
    const int bm = (blockIdx.x & 63) * 128;
    const int bn = (blockIdx.x >> 6) * 128;
    const int wm = (wave >> 1) * 64;
    const int wn = (wave & 1) * 64;

    const int srow = tid >> 2;
    const int skb  = (tid & 3) * 8;

    floatx4 acc[4][4] = {};

    auto stage = [&](int buf, int k0) {
        async_lds16(A + (size_t)(bm + srow) * K + skb + k0, &As[buf][tid * 8]);
        async_lds16(A + (size_t)(bm + 64 + srow) * K + skb + k0, &As[buf][2048 + tid * 8]);
        async_lds16(B + (size_t)(bn + srow) * K + skb + k0, &Bs[buf][tid * 8]);
        async_lds16(B + (size_t)(bn + 64 + srow) * K + skb + k0, &Bs[buf][2048 + tid * 8]);
    };

    stage(0, 0);
    for (int it = 0; it < K / 32; ++it) {
        __syncthreads();
        if (it + 1 < K / 32) stage((it + 1) & 1, (it + 1) * 32);
        const unsigned short* Ac = &As[it & 1][0];
        const unsigned short* Bc = &Bs[it & 1][0];

        bf16x8 af[4], bfr[4];
        #pragma unroll
        for (int i = 0; i < 4; ++i)
            af[i] = *(const bf16x8*)&Ac[(wm + i * 16 + l16) * 32 + quad * 8];
        #pragma unroll
        for (int j = 0; j < 4; ++j)
            bfr[j] = *(const bf16x8*)&Bc[(wn + j * 16 + l16) * 32 + quad * 8];
        #pragma unroll
        for (int i = 0; i < 4; ++i)
            #pragma unroll
            for (int j = 0; j < 4; ++j)
                acc[i][j] = MFMA_16x16x32(af[i], bfr[j], acc[i][j]);
    }

    if (z == 2) {
        __syncthreads();
        unsigned short* Tw = &As[0][0] + wave * (16 * 66);
        #pragma unroll
        for (int j = 0; j < 4; ++j) {
            const float bv = bias[bn + wn + j * 16 + l16] * bsc;
            #pragma unroll
            for (int i = 0; i < 4; ++i)
                #pragma unroll
                for (int r = 0; r < 4; ++r)
                    Tw[l16 * 66 + i * 16 + quad * 4 + r] = f2b(acc[i][j][r] + bv);
            __syncthreads();
            const int c2  = lane >> 2;
            const int tch = lane & 3;
            bf16x8 t0 = *(const bf16x8*)&Tw[c2 * 66 + tch * 16];
            bf16x8 t1 = *(const bf16x8*)&Tw[c2 * 66 + tch * 16 + 8];
            const size_t off = (size_t)(bn + wn + j * 16 + c2) * (size_t)M + (bm + wm + tch * 16);
            *(bf16x8*)&C[off]     = t0;
            *(bf16x8*)&C[off + 8] = t1;
            __syncthreads();
        }
    } else {
        #pragma unroll
        for (int i = 0; i < 4; ++i) {
            const int row = bm + wm + i * 16 + quad * 4;
            #pragma unroll
            for (int j = 0; j < 4; ++j) {
                const int col = bn + wn + j * 16 + l16;
                const float bv = bias[col] * bsc;
                #pragma unroll
                for (int r = 0; r < 4; ++r)
                    C[(size_t)(row + r) * N + col] = f2b(acc[i][j][r] + bv);
            }
        }
    }
}

// ---------------- output projection GEMM (bf16 A, fp32 out; dbuf + swizzle) ----------------
__global__ __launch_bounds__(256) void gemm_out(
    const unsigned short* __restrict__ A, const unsigned short* __restrict__ B,
    const float* __restrict__ bias, float* __restrict__ C,
    int M, int N, int K)
{
    __shared__ __align__(16) unsigned short As[2][4096];
    __shared__ __align__(16) unsigned short Bs[2][4096];

    const int tid  = threadIdx.x;
    const int wave = tid >> 6;
    const int lane = tid & 63;
    const int l16  = lane & 15;
    const int quad = lane >> 4;
    const int bm = (blockIdx.x & 63) * 128;
    const int bn = (blockIdx.x >> 6) * 128;
    const int wm = (wave >> 1) * 64;
    const int wn = (wave & 1) * 64;

    const int srow = tid >> 2;
    const int skb  = (tid & 3) * 8;

    floatx4 acc[4][4] = {};

    auto stage = [&](int buf, int k0) {
        async_lds16(A + (size_t)(bm + srow) * K + skb + k0, &As[buf][tid * 8]);
        async_lds16(A + (size_t)(bm + 64 + srow) * K + skb + k0, &As[buf][2048 + tid * 8]);
        async_lds16(B + (size_t)(bn + srow) * K + skb + k0, &Bs[buf][tid * 8]);
        async_lds16(B + (size_t)(bn + 64 + srow) * K + skb + k0, &Bs[buf][2048 + tid * 8]);
    };

    stage(0, 0);
    for (int it = 0; it < K / 32; ++it) {
        __syncthreads();
        if (it + 1 < K / 32) stage((it + 1) & 1, (it + 1) * 32);
        const unsigned short* Ac = &As[it & 1][0];
        const unsigned short* Bc = &Bs[it & 1][0];

        bf16x8 af[4], bfr[4];
        #pragma unroll
        for (int i = 0; i < 4; ++i)
            af[i] = *(const bf16x8*)&Ac[(wm + i * 16 + l16) * 32 + quad * 8];
        #pragma unroll
        for (int j = 0; j < 4; ++j)
            bfr[j] = *(const bf16x8*)&Bc[(wn + j * 16 + l16) * 32 + quad * 8];
        #pragma unroll
        for (int i = 0; i < 4; ++i)
            #pragma unroll
            for (int j = 0; j < 4; ++j)
                acc[i][j] = MFMA_16x16x32(af[i], bfr[j], acc[i][j]);
    }

    #pragma unroll
    for (int i = 0; i < 4; ++i) {
        const int row = bm + wm + i * 16 + quad * 4;
        #pragma unroll
        for (int j = 0; j < 4; ++j) {
            const int col = bn + wn + j * 16 + l16;
            const float bv = bias[col];
            #pragma unroll
            for (int r = 0; r < 4; ++r)
                C[(size_t)(row + r) * N + col] = acc[i][j][r] + bv;
        }
    }
}

// ---------------- flash attention v7: 8 waves x 32 q-rows (2x occupancy) ----------------
// Q (pre-scaled by log2e/8), K: bf16 [b][s][h*64+d]; Vt: bf16 [h*64+d][b*2048+s].
// Grid 512 (1D): bh = x & 63 (XCD affinity), qt = x >> 6. Block q-tile 256,
// 8 waves x 32 q each (512 threads); kv tiles of 64, double-buffered, 1-tile prefetch.
// LDS unchanged at 66 KB -> 2 blocks/CU, but 16 waves/CU (4/SIMD) instead of 8.
// S^T = K Q^T; P via wave-private LDS (stride 68); rowsum via ones-MFMA.
__global__ __launch_bounds__(512, 4) void attn_kernel(
    const unsigned short* __restrict__ Q, const unsigned short* __restrict__ Kg,
    const unsigned short* __restrict__ Vt, unsigned short* __restrict__ Y)
{
    __shared__ __align__(16) unsigned short Ks[2][4096];      // swizzled [kv][d]
    __shared__ __align__(16) unsigned short Vs[2][4096];      // swizzled [d][kv]
    __shared__ __align__(16) unsigned short Pt[8][32 * 68];   // per-wave [q][kv], stride 68

    const int tid  = threadIdx.x;
    const int wave = tid >> 6;      // 0..7
    const int lane = tid & 63;
    const int l16  = lane & 15;
    const int quad = lane >> 4;
    const int bh = blockIdx.x & 63;
    const int qt = blockIdx.x >> 6;
    const int b  = bh >> 4;
    const int h  = bh & 15;
    const int q0 = qt * 256 + wave * 32;
    const size_t base  = ((size_t)b * 2048) * 1024 + (size_t)h * 64;
    const size_t vbase = ((size_t)h * 64) * 8192 + (size_t)b * 2048;

    // Q fragments: qf[nt][kk], q = q0 + nt*16 + l16, d = kk*32 + quad*8 ..
    bf16x8 qf[2][2];
    #pragma unroll
    for (int nt = 0; nt < 2; ++nt) {
        const size_t qoff = base + (size_t)(q0 + nt * 16 + l16) * 1024 + quad * 8;
        qf[nt][0] = *(const bf16x8*)&Q[qoff];
        qf[nt][1] = *(const bf16x8*)&Q[qoff + 32];
    }

    bf16x8 ones;
    #pragma unroll
    for (int e = 0; e < 8; ++e) ones[e] = (short)0x3F80;   // bf16 1.0
    const floatx4 ZERO4 = {0.f, 0.f, 0.f, 0.f};

    floatx4 o[2][4] = {};   // [mq][nd]
    floatx4 rs[2] = {};     // rowsum denominators, C-layout like o

    const int rl_ = tid >> 3;           // 0..63 (staging row)
    const int cb  = tid & 7;
    const int csw = cb ^ (rl_ & 7);
    const int swz = l16 & 7;
    // hoisted swizzled block offsets for K/V fragment reads (elements)
    const int sw0 = (quad ^ swz) * 8;
    const int sw1 = ((4 + quad) ^ swz) * 8;
    const int krow = l16 * 64;          // K/V fragment row base (elements)
    const int prow = l16 * 68;          // Pt row base (elements)
    const int pcol = quad * 4;          // Pt write col base

    unsigned short* Pw = &Pt[wave][0];

    auto stage = [&](int buf, int kv0) {
        async_lds16(&Kg[base + (size_t)(kv0 + rl_) * 1024 + csw * 8], &Ks[buf][tid * 8]);
        async_lds16(&Vt[vbase + (size_t)rl_ * 8192 + kv0 + csw * 8], &Vs[buf][tid * 8]);
    };

    stage(0, 0);
    for (int t = 0; t < 32; ++t) {
        __syncthreads();
        if (t < 31) stage((t + 1) & 1, (t + 1) * 64);
        const unsigned short* Kc = &Ks[t & 1][0];
        const unsigned short* Vc = &Vs[t & 1][0];

        // S^T[kv][q] = K Q^T (softmax scale pre-folded into Q)
        floatx4 st[4][2];   // [mt][nt]
        #pragma unroll
        for (int mt = 0; mt < 4; ++mt) {
            const bf16x8 kf0 = *(const bf16x8*)&Kc[mt * 1024 + krow + sw0];
            const bf16x8 kf1 = *(const bf16x8*)&Kc[mt * 1024 + krow + sw1];
            #pragma unroll
            for (int nt = 0; nt < 2; ++nt) {
                st[mt][nt] = MFMA_16x16x32(kf0, qf[nt][0], ZERO4);
                st[mt][nt] = MFMA_16x16x32(kf1, qf[nt][1], st[mt][nt]);
            }
        }

        // P = 2^(S^T) packed bf16 (v_cvt_pk_bf16_f32), b64 stores to wave-private Pt
        #pragma unroll
        for (int mt = 0; mt < 4; ++mt) {
            #pragma unroll
            for (int nt = 0; nt < 2; ++nt) {
                uint2 w;
                w.x = pk2(__builtin_amdgcn_exp2f(st[mt][nt][0]),
                          __builtin_amdgcn_exp2f(st[mt][nt][1]));
                w.y = pk2(__builtin_amdgcn_exp2f(st[mt][nt][2]),
                          __builtin_amdgcn_exp2f(st[mt][nt][3]));
                *(uint2*)&Pw[nt * (16 * 68) + prow + mt * 16 + pcol] = w;
            }
        }

        // O += P V ; denominators += P @ ones (matrix pipe)
        #pragma unroll
        for (int kk = 0; kk < 2; ++kk) {
            const int swk = kk ? sw1 : sw0;
            bf16x8 pf[2];
            #pragma unroll
            for (int mq = 0; mq < 2; ++mq)
                pf[mq] = *(const bf16x8*)&Pw[mq * (16 * 68) + prow + kk * 32 + quad * 8];
            #pragma unroll
            for (int nd = 0; nd < 4; ++nd) {
                const bf16x8 vf = *(const bf16x8*)&Vc[nd * 1024 + krow + swk];
                #pragma unroll
                for (int mq = 0; mq < 2; ++mq)
                    o[mq][nd] = MFMA_16x16x32(pf[mq], vf, o[mq][nd]);
            }
            #pragma unroll
            for (int mq = 0; mq < 2; ++mq)
                rs[mq] = MFMA_16x16x32(pf[mq], ones, rs[mq]);
        }
    }

    // finalize: rs lane-layout matches o -> direct normalize
    #pragma unroll
    for (int mq = 0; mq < 2; ++mq) {
        #pragma unroll
        for (int r = 0; r < 4; ++r) {
            const float inv = 1.0f / rs[mq][r];
            const size_t row = q0 + mq * 16 + quad * 4 + r;
            #pragma unroll
            for (int nd = 0; nd < 4; ++nd)
                Y[base + row * 1024 + nd * 16 + l16] = f2b(o[mq][nd][r] * inv);
        }
    }
}

extern "C" void kernel_launch(void* const* d_in, const int* in_sizes, int n_in,
                              void* d_out, int out_size, void* d_ws, size_t ws_size,
                              hipStream_t stream)
{
    const float* dec = (const float*)d_in[0];
    const float* enc = (const float*)d_in[1];
    const float* Wq  = (const float*)d_in[2];
    const float* bq  = (const float*)d_in[3];
    const float* Wk  = (const float*)d_in[4];
    const float* bk  = (const float*)d_in[5];
    const float* Wv  = (const float*)d_in[6];
    const float* bv  = (const float*)d_in[7];
    const float* Wp  = (const float*)d_in[8];
    const float* bp  = (const float*)d_in[9];

    const size_t NTOK = 8192, DM = 1024;
    unsigned short* ws = (unsigned short*)d_ws;
    unsigned short* decB = ws;
    unsigned short* encB = decB + NTOK * DM;
    unsigned short* WqB  = encB + NTOK * DM;
    unsigned short* WkB  = WqB + DM * DM;
    unsigned short* WvB  = WkB + DM * DM;
    unsigned short* WpB  = WvB + DM * DM;
    unsigned short* Qb   = WpB + DM * DM;
    unsigned short* Kb   = Qb + NTOK * DM;
    unsigned short* VtG  = Kb + NTOK * DM;           // [1024][8192]
    unsigned short* Yb   = VtG + NTOK * DM;

    const float C_SM = 0.18033688f;   // log2(e) / sqrt(64)

    CvtArgs a;
    a.src[0] = dec; a.src[1] = enc; a.src[2] = Wq; a.src[3] = Wk; a.src[4] = Wv; a.src[5] = Wp;
    a.dst[0] = decB; a.dst[1] = encB; a.dst[2] = WqB; a.dst[3] = WkB; a.dst[4] = WvB; a.dst[5] = WpB;
    a.scale[0] = 1.f; a.scale[1] = 1.f; a.scale[2] = C_SM;
    a.scale[3] = 1.f; a.scale[4] = 1.f; a.scale[5] = 1.f;
    a.n8[0] = a.n8[1] = (int)(NTOK * DM / 8);
    a.n8[2] = a.n8[3] = a.n8[4] = a.n8[5] = (int)(DM * DM / 8);
    convert_kernel<<<dim3(4096, 6), 256, 0, stream>>>(a);

    QKVArgs qa;
    qa.A[0] = decB; qa.A[1] = encB; qa.A[2] = encB;
    qa.B[0] = WqB;  qa.B[1] = WkB;  qa.B[2] = WvB;
    qa.bias[0] = bq; qa.bias[1] = bk; qa.bias[2] = bv;
    qa.bscale[0] = C_SM; qa.bscale[1] = 1.f; qa.bscale[2] = 1.f;
    qa.C[0] = Qb;   qa.C[1] = Kb;   qa.C[2] = VtG;
    gemm_qkv<<<dim3(512, 1, 3), 256, 0, stream>>>(qa);

    attn_kernel<<<dim3(512), 512, 0, stream>>>(Qb, Kb, VtG, Yb);
    gemm_out<<<dim3(512), 256, 0, stream>>>(Yb, WpB, bp, (float*)d_out, 8192, 1024, 1024);
}

// Round 2
// 347.371 us; speedup vs baseline: 1.0543x; 1.0089x over previous
//
#include <hip/hip_runtime.h>
#include <hip/hip_bf16.h>

typedef __attribute__((ext_vector_type(8))) short bf16x8;   // 8 bf16 in 4 VGPRs
typedef __attribute__((ext_vector_type(4))) float floatx4;

#define MFMA_16x16x32(A, B, C) __builtin_amdgcn_mfma_f32_16x16x32_bf16(A, B, C, 0, 0, 0)

__device__ __forceinline__ unsigned short f2b(float f) {
    __hip_bfloat16 h = __float2bfloat16(f);  // RNE
    unsigned short u;
    __builtin_memcpy(&u, &h, 2);
    return u;
}
// pack 2 floats -> 2 bf16 (RNE) in one u32 (v_cvt_pk_bf16_f32 on gfx950)
__device__ __forceinline__ unsigned pk2(float a, float b) {
    __hip_bfloat162 h = __float22bfloat162_rn(float2{a, b});
    unsigned u;
    __builtin_memcpy(&u, &h, 4);
    return u;
}
__device__ __forceinline__ void async_lds16(const void* g, void* l) {
    __builtin_amdgcn_global_load_lds((__attribute__((address_space(1))) void*)g,
                                     (__attribute__((address_space(3))) void*)l, 16, 0, 0);
}

// ---------------- fp32 -> bf16 bulk convert (with per-tensor scale) ----------------
struct CvtArgs {
    const float* src[6];
    unsigned short* dst[6];
    float scale[6];
    int n8[6];
};
__global__ __launch_bounds__(256) void convert_kernel(CvtArgs a) {
    const int t = blockIdx.y;
    const int i = blockIdx.x * 256 + threadIdx.x;
    if (i >= a.n8[t]) return;
    const float sc = a.scale[t];
    const float4* s = (const float4*)a.src[t];
    const float4 x = s[2 * i], y = s[2 * i + 1];
    bf16x8 v;
    v[0] = (short)f2b(x.x * sc); v[1] = (short)f2b(x.y * sc);
    v[2] = (short)f2b(x.z * sc); v[3] = (short)f2b(x.w * sc);
    v[4] = (short)f2b(y.x * sc); v[5] = (short)f2b(y.y * sc);
    v[6] = (short)f2b(y.z * sc); v[7] = (short)f2b(y.w * sc);
    *(bf16x8*)(a.dst[t] + (size_t)i * 8) = v;
}

// ---------------- fused QKV projection GEMM (double-buffered, XCD-swizzled) ----------------
struct QKVArgs {
    const unsigned short* A[3];
    const unsigned short* B[3];
    const float* bias[3];
    float bscale[3];
    unsigned short* C[3];
};
__global__ __launch_bounds__(256) void gemm_qkv(QKVArgs args) {
    constexpr int M = 8192, N = 1024, K = 1024;
    __shared__ __align__(16) unsigned short As[2][4096];
    __shared__ __align__(16) unsigned short Bs[2][4096];

    const int z = blockIdx.z;
    const unsigned short* __restrict__ A = args.A[z];
    const unsigned short* __restrict__ B = args.B[z];
    const float* __restrict__ bias = args.bias[z];
    const float bsc = args.bscale[z];
    unsigned short* __restrict__ C = args.C[z];

    const int tid  = threadIdx.x;
    const int wave = tid >> 6;
    const int lane = tid & 63;
    const int l16  = lane & 15;
    const int quad = lane >> 4;
    const int bm = (blockIdx.x & 63) * 128;
    const int bn = (blockIdx.x >> 6) * 128;
    const int wm = (wave >> 1) * 64;
    const int wn = (wave & 1) * 64;

    const int srow = tid >> 2;
    const int skb  = (tid & 3) * 8;

    floatx4 acc[4][4] = {};

    auto stage = [&](int buf, int k0) {
        async_lds16(A + (size_t)(bm + srow) * K + skb + k0, &As[buf][tid * 8]);
        async_lds16(A + (size_t)(bm + 64 + srow) * K + skb + k0, &As[buf][2048 + tid * 8]);
        async_lds16(B + (size_t)(bn + srow) * K + skb + k0, &Bs[buf][tid * 8]);
        async_lds16(B + (size_t)(bn + 64 + srow) * K + skb + k0, &Bs[buf][2048 + tid * 8]);
    };

    stage(0, 0);
    for (int it = 0; it < K / 32; ++it) {
        __syncthreads();
        if (it + 1 < K / 32) stage((it + 1) & 1, (it + 1) * 32);
        const unsigned short* Ac = &As[it & 1][0];
        const unsigned short* Bc = &Bs[it & 1][0];

        bf16x8 af[4], bfr[4];
        #pragma unroll
        for (int i = 0; i < 4; ++i)
            af[i] = *(const bf16x8*)&Ac[(wm + i * 16 + l16) * 32 + quad * 8];
        #pragma unroll
        for (int j = 0; j < 4; ++j)
            bfr[j] = *(const bf16x8*)&Bc[(wn + j * 16 + l16) * 32 + quad * 8];
        #pragma unroll
        for (int i = 0; i < 4; ++i)
            #pragma unroll
            for (int j = 0; j < 4; ++j)
                acc[i][j] = MFMA_16x16x32(af[i], bfr[j], acc[i][j]);
    }

    if (z == 2) {
        __syncthreads();
        unsigned short* Tw = &As[0][0] + wave * (16 * 66);
        #pragma unroll
        for (int j = 0; j < 4; ++j) {
            const float bv = bias[bn + wn + j * 16 + l16] * bsc;
            #pragma unroll
            for (int i = 0; i < 4; ++i)
                #pragma unroll
                for (int r = 0; r < 4; ++r)
                    Tw[l16 * 66 + i * 16 + quad * 4 + r] = f2b(acc[i][j][r] + bv);
            __syncthreads();
            const int c2  = lane >> 2;
            const int tch = lane & 3;
            bf16x8 t0 = *(const bf16x8*)&Tw[c2 * 66 + tch * 16];
            bf16x8 t1 = *(const bf16x8*)&Tw[c2 * 66 + tch * 16 + 8];
            const size_t off = (size_t)(bn + wn + j * 16 + c2) * (size_t)M + (bm + wm + tch * 16);
            *(bf16x8*)&C[off]     = t0;
            *(bf16x8*)&C[off + 8] = t1;
            __syncthreads();
        }
    } else {
        #pragma unroll
        for (int i = 0; i < 4; ++i) {
            const int row = bm + wm + i * 16 + quad * 4;
            #pragma unroll
            for (int j = 0; j < 4; ++j) {
                const int col = bn + wn + j * 16 + l16;
                const float bv = bias[col] * bsc;
                #pragma unroll
                for (int r = 0; r < 4; ++r)
                    C[(size_t)(row + r) * N + col] = f2b(acc[i][j][r] + bv);
            }
        }
    }
}

// ---------------- output projection GEMM (bf16 A, fp32 out; dbuf + swizzle) ----------------
__global__ __launch_bounds__(256) void gemm_out(
    const unsigned short* __restrict__ A, const unsigned short* __restrict__ B,
    const float* __restrict__ bias, float* __restrict__ C,
    int M, int N, int K)
{
    __shared__ __align__(16) unsigned short As[2][4096];
    __shared__ __align__(16) unsigned short Bs[2][4096];

    const int tid  = threadIdx.x;
    const int wave = tid >> 6;
    const int lane = tid & 63;
    const int l16  = lane & 15;
    const int quad = lane >> 4;
    const int bm = (blockIdx.x & 63) * 128;
    const int bn = (blockIdx.x >> 6) * 128;
    const int wm = (wave >> 1) * 64;
    const int wn = (wave & 1) * 64;

    const int srow = tid >> 2;
    const int skb  = (tid & 3) * 8;

    floatx4 acc[4][4] = {};

    auto stage = [&](int buf, int k0) {
        async_lds16(A + (size_t)(bm + srow) * K + skb + k0, &As[buf][tid * 8]);
        async_lds16(A + (size_t)(bm + 64 + srow) * K + skb + k0, &As[buf][2048 + tid * 8]);
        async_lds16(B + (size_t)(bn + srow) * K + skb + k0, &Bs[buf][tid * 8]);
        async_lds16(B + (size_t)(bn + 64 + srow) * K + skb + k0, &Bs[buf][2048 + tid * 8]);
    };

    stage(0, 0);
    for (int it = 0; it < K / 32; ++it) {
        __syncthreads();
        if (it + 1 < K / 32) stage((it + 1) & 1, (it + 1) * 32);
        const unsigned short* Ac = &As[it & 1][0];
        const unsigned short* Bc = &Bs[it & 1][0];

        bf16x8 af[4], bfr[4];
        #pragma unroll
        for (int i = 0; i < 4; ++i)
            af[i] = *(const bf16x8*)&Ac[(wm + i * 16 + l16) * 32 + quad * 8];
        #pragma unroll
        for (int j = 0; j < 4; ++j)
            bfr[j] = *(const bf16x8*)&Bc[(wn + j * 16 + l16) * 32 + quad * 8];
        #pragma unroll
        for (int i = 0; i < 4; ++i)
            #pragma unroll
            for (int j = 0; j < 4; ++j)
                acc[i][j] = MFMA_16x16x32(af[i], bfr[j], acc[i][j]);
    }

    #pragma unroll
    for (int i = 0; i < 4; ++i) {
        const int row = bm + wm + i * 16 + quad * 4;
        #pragma unroll
        for (int j = 0; j < 4; ++j) {
            const int col = bn + wn + j * 16 + l16;
            const float bv = bias[col];
            #pragma unroll
            for (int r = 0; r < 4; ++r)
                C[(size_t)(row + r) * N + col] = acc[i][j][r] + bv;
        }
    }
}

// ---------------- flash attention v8: software-pipelined S(t+1) || PV(t) ----------------
// Q (pre-scaled by log2e/8), K: bf16 [b][s][h*64+d]; Vt: bf16 [h*64+d][b*2048+s].
// Grid 512: bh = x & 63 (XCD affinity), qt = x >> 6. 8 waves x 32 q (512 thr).
// kv tiles of 64. K double-buffered (dist-1); V TRIPLE-buffered (dist-2 prefetch).
// Iteration t: stage K(t+2)/V(t+2); S-MFMA(t+1); PV(t) [reads P(t) from Pt];
// exp+P(t+1)-write LAST (same-wave DS in-order + alias keeps WAR on Pt safe).
// This overlaps the exp/trans chain of tile t+1 with PV MFMAs of tile t within
// one wave, breaking the per-tile serial convoy. LDS 75776 B -> 2 blocks/CU.
__global__ __launch_bounds__(512, 4) void attn_kernel(
    const unsigned short* __restrict__ Q, const unsigned short* __restrict__ Kg,
    const unsigned short* __restrict__ Vt, unsigned short* __restrict__ Y)
{
    __shared__ __align__(16) unsigned short Ks[2][4096];      // swizzled [kv][d]
    __shared__ __align__(16) unsigned short Vs[3][4096];      // swizzled [d][kv], triple buf
    __shared__ __align__(16) unsigned short Pt[8][32 * 68];   // per-wave [q][kv], stride 68

    const int tid  = threadIdx.x;
    const int wave = tid >> 6;      // 0..7
    const int lane = tid & 63;
    const int l16  = lane & 15;
    const int quad = lane >> 4;
    const int bh = blockIdx.x & 63;
    const int qt = blockIdx.x >> 6;
    const int b  = bh >> 4;
    const int h  = bh & 15;
    const int q0 = qt * 256 + wave * 32;
    const size_t base  = ((size_t)b * 2048) * 1024 + (size_t)h * 64;
    const size_t vbase = ((size_t)h * 64) * 8192 + (size_t)b * 2048;

    // Q fragments: qf[nt][kk], q = q0 + nt*16 + l16, d = kk*32 + quad*8 ..
    bf16x8 qf[2][2];
    #pragma unroll
    for (int nt = 0; nt < 2; ++nt) {
        const size_t qoff = base + (size_t)(q0 + nt * 16 + l16) * 1024 + quad * 8;
        qf[nt][0] = *(const bf16x8*)&Q[qoff];
        qf[nt][1] = *(const bf16x8*)&Q[qoff + 32];
    }

    bf16x8 ones;
    #pragma unroll
    for (int e = 0; e < 8; ++e) ones[e] = (short)0x3F80;   // bf16 1.0
    const floatx4 ZERO4 = {0.f, 0.f, 0.f, 0.f};

    floatx4 o[2][4] = {};   // [mq][nd]
    floatx4 rs[2] = {};     // rowsum denominators, C-layout like o

    const int rl_ = tid >> 3;           // 0..63 (staging row)
    const int cb  = tid & 7;
    const int csw = cb ^ (rl_ & 7);
    const int swz = l16 & 7;
    // hoisted swizzled block offsets for K/V fragment reads (elements)
    const int sw0 = (quad ^ swz) * 8;
    const int sw1 = ((4 + quad) ^ swz) * 8;
    const int krow = l16 * 64;          // K/V fragment row base (elements)
    const int prow = l16 * 68;          // Pt row base (elements)
    const int pcol = quad * 4;          // Pt write col base

    unsigned short* Pw = &Pt[wave][0];

    auto stageK = [&](int buf, int kv0) {
        async_lds16(&Kg[base + (size_t)(kv0 + rl_) * 1024 + csw * 8], &Ks[buf][tid * 8]);
    };
    auto stageV = [&](int buf, int kv0) {
        async_lds16(&Vt[vbase + (size_t)rl_ * 8192 + kv0 + csw * 8], &Vs[buf][tid * 8]);
    };

    // ---- prologue: stage tiles 0,1; compute S(0) -> P(0) ----
    stageK(0, 0);  stageV(0, 0);
    stageK(1, 64); stageV(1, 64);
    __syncthreads();
    {
        const unsigned short* Kc = &Ks[0][0];
        floatx4 st[4][2];
        #pragma unroll
        for (int mt = 0; mt < 4; ++mt) {
            const bf16x8 kf0 = *(const bf16x8*)&Kc[mt * 1024 + krow + sw0];
            const bf16x8 kf1 = *(const bf16x8*)&Kc[mt * 1024 + krow + sw1];
            #pragma unroll
            for (int nt = 0; nt < 2; ++nt) {
                st[mt][nt] = MFMA_16x16x32(kf0, qf[nt][0], ZERO4);
                st[mt][nt] = MFMA_16x16x32(kf1, qf[nt][1], st[mt][nt]);
            }
        }
        #pragma unroll
        for (int mt = 0; mt < 4; ++mt) {
            #pragma unroll
            for (int nt = 0; nt < 2; ++nt) {
                uint2 w;
                w.x = pk2(__builtin_amdgcn_exp2f(st[mt][nt][0]),
                          __builtin_amdgcn_exp2f(st[mt][nt][1]));
                w.y = pk2(__builtin_amdgcn_exp2f(st[mt][nt][2]),
                          __builtin_amdgcn_exp2f(st[mt][nt][3]));
                *(uint2*)&Pw[nt * (16 * 68) + prow + mt * 16 + pcol] = w;
            }
        }
    }

    int vcur = 0;   // vbuf holding V(t)
    int vstg = 2;   // vbuf receiving V(t+2)

    for (int t = 0; t < 32; ++t) {
        __syncthreads();    // K(t+2) dest freed (S(t) done); V(t-1) buf freed
        if (t < 30) { stageK(t & 1, (t + 2) * 64); stageV(vstg, (t + 2) * 64); }

        // ---- S(t+1) matrix phase (independent of PV(t)) ----
        floatx4 st[4][2];
        __builtin_amdgcn_s_setprio(1);
        if (t < 31) {
            const unsigned short* Kc = &Ks[(t + 1) & 1][0];
            #pragma unroll
            for (int mt = 0; mt < 4; ++mt) {
                const bf16x8 kf0 = *(const bf16x8*)&Kc[mt * 1024 + krow + sw0];
                const bf16x8 kf1 = *(const bf16x8*)&Kc[mt * 1024 + krow + sw1];
                #pragma unroll
                for (int nt = 0; nt < 2; ++nt) {
                    st[mt][nt] = MFMA_16x16x32(kf0, qf[nt][0], ZERO4);
                    st[mt][nt] = MFMA_16x16x32(kf1, qf[nt][1], st[mt][nt]);
                }
            }
        }

        // ---- PV(t): O += P(t) V(t); rowsum += P(t) @ ones ----
        {
            const unsigned short* Vc = &Vs[vcur][0];
            #pragma unroll
            for (int kk = 0; kk < 2; ++kk) {
                const int swk = kk ? sw1 : sw0;
                bf16x8 pf[2];
                #pragma unroll
                for (int mq = 0; mq < 2; ++mq)
                    pf[mq] = *(const bf16x8*)&Pw[mq * (16 * 68) + prow + kk * 32 + quad * 8];
                #pragma unroll
                for (int nd = 0; nd < 4; ++nd) {
                    const bf16x8 vf = *(const bf16x8*)&Vc[nd * 1024 + krow + swk];
                    #pragma unroll
                    for (int mq = 0; mq < 2; ++mq)
                        o[mq][nd] = MFMA_16x16x32(pf[mq], vf, o[mq][nd]);
                }
                #pragma unroll
                for (int mq = 0; mq < 2; ++mq)
                    rs[mq] = MFMA_16x16x32(pf[mq], ones, rs[mq]);
            }
        }
        __builtin_amdgcn_s_setprio(0);

        // ---- exp + P(t+1) store (after PV's P-reads; same-wave DS is in-order) ----
        if (t < 31) {
            #pragma unroll
            for (int mt = 0; mt < 4; ++mt) {
                #pragma unroll
                for (int nt = 0; nt < 2; ++nt) {
                    uint2 w;
                    w.x = pk2(__builtin_amdgcn_exp2f(st[mt][nt][0]),
                              __builtin_amdgcn_exp2f(st[mt][nt][1]));
                    w.y = pk2(__builtin_amdgcn_exp2f(st[mt][nt][2]),
                              __builtin_amdgcn_exp2f(st[mt][nt][3]));
                    *(uint2*)&Pw[nt * (16 * 68) + prow + mt * 16 + pcol] = w;
                }
            }
        }

        vcur = (vcur == 2) ? 0 : vcur + 1;
        vstg = (vstg == 2) ? 0 : vstg + 1;
    }

    // finalize: rs lane-layout matches o -> direct normalize
    #pragma unroll
    for (int mq = 0; mq < 2; ++mq) {
        #pragma unroll
        for (int r = 0; r < 4; ++r) {
            const float inv = 1.0f / rs[mq][r];
            const size_t row = q0 + mq * 16 + quad * 4 + r;
            #pragma unroll
            for (int nd = 0; nd < 4; ++nd)
                Y[base + row * 1024 + nd * 16 + l16] = f2b(o[mq][nd][r] * inv);
        }
    }
}

extern "C" void kernel_launch(void* const* d_in, const int* in_sizes, int n_in,
                              void* d_out, int out_size, void* d_ws, size_t ws_size,
                              hipStream_t stream)
{
    const float* dec = (const float*)d_in[0];
    const float* enc = (const float*)d_in[1];
    const float* Wq  = (const float*)d_in[2];
    const float* bq  = (const float*)d_in[3];
    const float* Wk  = (const float*)d_in[4];
    const float* bk  = (const float*)d_in[5];
    const float* Wv  = (const float*)d_in[6];
    const float* bv  = (const float*)d_in[7];
    const float* Wp  = (const float*)d_in[8];
    const float* bp  = (const float*)d_in[9];

    const size_t NTOK = 8192, DM = 1024;
    unsigned short* ws = (unsigned short*)d_ws;
    unsigned short* decB = ws;
    unsigned short* encB = decB + NTOK * DM;
    unsigned short* WqB  = encB + NTOK * DM;
    unsigned short* WkB  = WqB + DM * DM;
    unsigned short* WvB  = WkB + DM * DM;
    unsigned short* WpB  = WvB + DM * DM;
    unsigned short* Qb   = WpB + DM * DM;
    unsigned short* Kb   = Qb + NTOK * DM;
    unsigned short* VtG  = Kb + NTOK * DM;           // [1024][8192]
    unsigned short* Yb   = VtG + NTOK * DM;

    const float C_SM = 0.18033688f;   // log2(e) / sqrt(64)

    CvtArgs a;
    a.src[0] = dec; a.src[1] = enc; a.src[2] = Wq; a.src[3] = Wk; a.src[4] = Wv; a.src[5] = Wp;
    a.dst[0] = decB; a.dst[1] = encB; a.dst[2] = WqB; a.dst[3] = WkB; a.dst[4] = WvB; a.dst[5] = WpB;
    a.scale[0] = 1.f; a.scale[1] = 1.f; a.scale[2] = C_SM;
    a.scale[3] = 1.f; a.scale[4] = 1.f; a.scale[5] = 1.f;
    a.n8[0] = a.n8[1] = (int)(NTOK * DM / 8);
    a.n8[2] = a.n8[3] = a.n8[4] = a.n8[5] = (int)(DM * DM / 8);
    convert_kernel<<<dim3(4096, 6), 256, 0, stream>>>(a);

    QKVArgs qa;
    qa.A[0] = decB; qa.A[1] = encB; qa.A[2] = encB;
    qa.B[0] = WqB;  qa.B[1] = WkB;  qa.B[2] = WvB;
    qa.bias[0] = bq; qa.bias[1] = bk; qa.bias[2] = bv;
    qa.bscale[0] = C_SM; qa.bscale[1] = 1.f; qa.bscale[2] = 1.f;
    qa.C[0] = Qb;   qa.C[1] = Kb;   qa.C[2] = VtG;
    gemm_qkv<<<dim3(512, 1, 3), 256, 0, stream>>>(qa);

    attn_kernel<<<dim3(512), 512, 0, stream>>>(Qb, Kb, VtG, Yb);
    gemm_out<<<dim3(512), 256, 0, stream>>>(Yb, WpB, bp, (float*)d_out, 8192, 1024, 1024);
}

// Round 3
// 324.752 us; speedup vs baseline: 1.1278x; 1.0696x over previous
//
#include <hip/hip_runtime.h>
#include <hip/hip_bf16.h>

typedef __attribute__((ext_vector_type(8))) short bf16x8;   // 8 bf16 in 4 VGPRs
typedef __attribute__((ext_vector_type(4))) float floatx4;
typedef __attribute__((ext_vector_type(16))) float floatx16;
typedef __attribute__((ext_vector_type(2))) int int2v;

#define MFMA_16x16x32(A, B, C) __builtin_amdgcn_mfma_f32_16x16x32_bf16(A, B, C, 0, 0, 0)
#define MFMA_32x32x16(A, B, C) __builtin_amdgcn_mfma_f32_32x32x16_bf16(A, B, C, 0, 0, 0)

__device__ __forceinline__ unsigned short f2b(float f) {
    __hip_bfloat16 h = __float2bfloat16(f);  // RNE
    unsigned short u;
    __builtin_memcpy(&u, &h, 2);
    return u;
}
// pack 2 floats -> 2 bf16 (RNE) in one u32 (v_cvt_pk_bf16_f32 on gfx950)
__device__ __forceinline__ unsigned pk2(float a, float b) {
    __hip_bfloat162 h = __float22bfloat162_rn(float2{a, b});
    unsigned u;
    __builtin_memcpy(&u, &h, 4);
    return u;
}
__device__ __forceinline__ bf16x8 mk8(int a, int b, int c, int d) {
    union { int u[4]; bf16x8 v; } x;
    x.u[0] = a; x.u[1] = b; x.u[2] = c; x.u[3] = d;
    return x.v;
}
__device__ __forceinline__ void async_lds16(const void* g, void* l) {
    __builtin_amdgcn_global_load_lds((__attribute__((address_space(1))) void*)g,
                                     (__attribute__((address_space(3))) void*)l, 16, 0, 0);
}

// ---------------- fp32 -> bf16 bulk convert (with per-tensor scale) ----------------
struct CvtArgs {
    const float* src[6];
    unsigned short* dst[6];
    float scale[6];
    int n8[6];
};
__global__ __launch_bounds__(256) void convert_kernel(CvtArgs a) {
    const int t = blockIdx.y;
    const int i = blockIdx.x * 256 + threadIdx.x;
    if (i >= a.n8[t]) return;
    const float sc = a.scale[t];
    const float4* s = (const float4*)a.src[t];
    const float4 x = s[2 * i], y = s[2 * i + 1];
    bf16x8 v;
    v[0] = (short)f2b(x.x * sc); v[1] = (short)f2b(x.y * sc);
    v[2] = (short)f2b(x.z * sc); v[3] = (short)f2b(x.w * sc);
    v[4] = (short)f2b(y.x * sc); v[5] = (short)f2b(y.y * sc);
    v[6] = (short)f2b(y.z * sc); v[7] = (short)f2b(y.w * sc);
    *(bf16x8*)(a.dst[t] + (size_t)i * 8) = v;
}

// ---------------- fused QKV projection GEMM (double-buffered, XCD-swizzled) ----------------
struct QKVArgs {
    const unsigned short* A[3];
    const unsigned short* B[3];
    const float* bias[3];
    float bscale[3];
    unsigned short* C[3];
};
__global__ __launch_bounds__(256) void gemm_qkv(QKVArgs args) {
    constexpr int M = 8192, N = 1024, K = 1024;
    __shared__ __align__(16) unsigned short As[2][4096];
    __shared__ __align__(16) unsigned short Bs[2][4096];

    const int z = blockIdx.z;
    const unsigned short* __restrict__ A = args.A[z];
    const unsigned short* __restrict__ B = args.B[z];
    const float* __restrict__ bias = args.bias[z];
    const float bsc = args.bscale[z];
    unsigned short* __restrict__ C = args.C[z];

    const int tid  = threadIdx.x;
    const int wave = tid >> 6;
    const int lane = tid & 63;
    const int l16  = lane & 15;
    const int quad = lane >> 4;
    const int bm = (blockIdx.x & 63) * 128;
    const int bn = (blockIdx.x >> 6) * 128;
    const int wm = (wave >> 1) * 64;
    const int wn = (wave & 1) * 64;

    const int srow = tid >> 2;
    const int skb  = (tid & 3) * 8;

    floatx4 acc[4][4] = {};

    auto stage = [&](int buf, int k0) {
        async_lds16(A + (size_t)(bm + srow) * K + skb + k0, &As[buf][tid * 8]);
        async_lds16(A + (size_t)(bm + 64 + srow) * K + skb + k0, &As[buf][2048 + tid * 8]);
        async_lds16(B + (size_t)(bn + srow) * K + skb + k0, &Bs[buf][tid * 8]);
        async_lds16(B + (size_t)(bn + 64 + srow) * K + skb + k0, &Bs[buf][2048 + tid * 8]);
    };

    stage(0, 0);
    for (int it = 0; it < K / 32; ++it) {
        __syncthreads();
        if (it + 1 < K / 32) stage((it + 1) & 1, (it + 1) * 32);
        const unsigned short* Ac = &As[it & 1][0];
        const unsigned short* Bc = &Bs[it & 1][0];

        bf16x8 af[4], bfr[4];
        #pragma unroll
        for (int i = 0; i < 4; ++i)
            af[i] = *(const bf16x8*)&Ac[(wm + i * 16 + l16) * 32 + quad * 8];
        #pragma unroll
        for (int j = 0; j < 4; ++j)
            bfr[j] = *(const bf16x8*)&Bc[(wn + j * 16 + l16) * 32 + quad * 8];
        #pragma unroll
        for (int i = 0; i < 4; ++i)
            #pragma unroll
            for (int j = 0; j < 4; ++j)
                acc[i][j] = MFMA_16x16x32(af[i], bfr[j], acc[i][j]);
    }

    if (z == 2) {
        __syncthreads();
        unsigned short* Tw = &As[0][0] + wave * (16 * 66);
        #pragma unroll
        for (int j = 0; j < 4; ++j) {
            const float bv = bias[bn + wn + j * 16 + l16] * bsc;
            #pragma unroll
            for (int i = 0; i < 4; ++i)
                #pragma unroll
                for (int r = 0; r < 4; ++r)
                    Tw[l16 * 66 + i * 16 + quad * 4 + r] = f2b(acc[i][j][r] + bv);
            __syncthreads();
            const int c2  = lane >> 2;
            const int tch = lane & 3;
            bf16x8 t0 = *(const bf16x8*)&Tw[c2 * 66 + tch * 16];
            bf16x8 t1 = *(const bf16x8*)&Tw[c2 * 66 + tch * 16 + 8];
            const size_t off = (size_t)(bn + wn + j * 16 + c2) * (size_t)M + (bm + wm + tch * 16);
            *(bf16x8*)&C[off]     = t0;
            *(bf16x8*)&C[off + 8] = t1;
            __syncthreads();
        }
    } else {
        #pragma unroll
        for (int i = 0; i < 4; ++i) {
            const int row = bm + wm + i * 16 + quad * 4;
            #pragma unroll
            for (int j = 0; j < 4; ++j) {
                const int col = bn + wn + j * 16 + l16;
                const float bv = bias[col] * bsc;
                #pragma unroll
                for (int r = 0; r < 4; ++r)
                    C[(size_t)(row + r) * N + col] = f2b(acc[i][j][r] + bv);
            }
        }
    }
}

// ---------------- output projection GEMM (bf16 A, fp32 out; dbuf + swizzle) ----------------
__global__ __launch_bounds__(256) void gemm_out(
    const unsigned short* __restrict__ A, const unsigned short* __restrict__ B,
    const float* __restrict__ bias, float* __restrict__ C,
    int M, int N, int K)
{
    __shared__ __align__(16) unsigned short As[2][4096];
    __shared__ __align__(16) unsigned short Bs[2][4096];

    const int tid  = threadIdx.x;
    const int wave = tid >> 6;
    const int lane = tid & 63;
    const int l16  = lane & 15;
    const int quad = lane >> 4;
    const int bm = (blockIdx.x & 63) * 128;
    const int bn = (blockIdx.x >> 6) * 128;
    const int wm = (wave >> 1) * 64;
    const int wn = (wave & 1) * 64;

    const int srow = tid >> 2;
    const int skb  = (tid & 3) * 8;

    floatx4 acc[4][4] = {};

    auto stage = [&](int buf, int k0) {
        async_lds16(A + (size_t)(bm + srow) * K + skb + k0, &As[buf][tid * 8]);
        async_lds16(A + (size_t)(bm + 64 + srow) * K + skb + k0, &As[buf][2048 + tid * 8]);
        async_lds16(B + (size_t)(bn + srow) * K + skb + k0, &Bs[buf][tid * 8]);
        async_lds16(B + (size_t)(bn + 64 + srow) * K + skb + k0, &Bs[buf][2048 + tid * 8]);
    };

    stage(0, 0);
    for (int it = 0; it < K / 32; ++it) {
        __syncthreads();
        if (it + 1 < K / 32) stage((it + 1) & 1, (it + 1) * 32);
        const unsigned short* Ac = &As[it & 1][0];
        const unsigned short* Bc = &Bs[it & 1][0];

        bf16x8 af[4], bfr[4];
        #pragma unroll
        for (int i = 0; i < 4; ++i)
            af[i] = *(const bf16x8*)&Ac[(wm + i * 16 + l16) * 32 + quad * 8];
        #pragma unroll
        for (int j = 0; j < 4; ++j)
            bfr[j] = *(const bf16x8*)&Bc[(wn + j * 16 + l16) * 32 + quad * 8];
        #pragma unroll
        for (int i = 0; i < 4; ++i)
            #pragma unroll
            for (int j = 0; j < 4; ++j)
                acc[i][j] = MFMA_16x16x32(af[i], bfr[j], acc[i][j]);
    }

    #pragma unroll
    for (int i = 0; i < 4; ++i) {
        const int row = bm + wm + i * 16 + quad * 4;
        #pragma unroll
        for (int j = 0; j < 4; ++j) {
            const int col = bn + wn + j * 16 + l16;
            const float bv = bias[col];
            #pragma unroll
            for (int r = 0; r < 4; ++r)
                C[(size_t)(row + r) * N + col] = acc[i][j][r] + bv;
        }
    }
}

// ---------------- flash attention v9: 32x32 MFMA + in-register P transpose ----------------
// Q (pre-scaled by log2e/8), K: bf16 [b][s][h*64+d]; Vt: bf16 [h*64+d][b*2048+s].
// Grid 1024: bh = x & 63 (XCD affinity: 64%8==0 keeps all qt of a bh on one XCD),
// qt = x >> 6 (0..15). 4 waves x 32 q = 128 q/block, 256 threads.
// Per kv-tile (64): S^T (2x 32x32 blocks, 4 k-steps of d) -> exp2 -> cvt_pk ->
// v_permlane32_swap builds PV A-fragments IN REGISTERS (no P LDS round trip).
// Rowsum = VALU adds on exp'd f32 (off the matrix pipe). LDS 33 KB -> 4 blocks/CU:
// barriers phase-lock only 4 waves; 4 independent blocks/CU give cross-block overlap.
__global__ __launch_bounds__(256, 4) void attn_kernel(
    const unsigned short* __restrict__ Q, const unsigned short* __restrict__ Kg,
    const unsigned short* __restrict__ Vt, unsigned short* __restrict__ Y)
{
    __shared__ __align__(16) unsigned short Ks[2][4096];   // swizzled [kv(64)][d(64)]
    __shared__ __align__(16) unsigned short Vs[2][4096];   // swizzled [d(64)][kv(64)]
    __shared__ float rsb[4][32];                           // per-wave rowsum transpose

    const int tid  = threadIdx.x;
    const int wave = tid >> 6;      // 0..3
    const int lane = tid & 63;
    const int l31  = lane & 31;
    const int hi   = lane >> 5;     // 0/1
    const int x7   = lane & 7;
    const int bh = blockIdx.x & 63;
    const int qt = blockIdx.x >> 6;
    const int b  = bh >> 4;
    const int h  = bh & 15;
    const int q0 = qt * 128 + wave * 32;
    const size_t base  = ((size_t)b * 2048) * 1024 + (size_t)h * 64;
    const size_t vbase = ((size_t)h * 64) * 8192 + (size_t)b * 2048;

    // Q fragments (B-operand, 32x32x16): qf[ks] = Q[q0 + l31][d = ks*16 + hi*8 .. +8]
    bf16x8 qf[4];
    {
        const size_t qrow = base + (size_t)(q0 + l31) * 1024 + hi * 8;
        #pragma unroll
        for (int ks = 0; ks < 4; ++ks)
            qf[ks] = *(const bf16x8*)&Q[qrow + ks * 16];
    }

    const floatx16 Z16 = {0.f,0.f,0.f,0.f,0.f,0.f,0.f,0.f,
                          0.f,0.f,0.f,0.f,0.f,0.f,0.f,0.f};

    floatx16 o0 = Z16, o1 = Z16;    // O[q(rows)][d = nd*32 + l31]
    float racc = 0.f;               // rowsum partial (lane's kv rows, col q=l31)

    // staging: 256 threads, rows r0 / r0+32, XOR-swizzled source col, linear LDS dest
    const int r0  = tid >> 3;             // 0..31
    const int csw = (tid & 7) ^ (r0 & 7); // same for r0 and r0+32

    // hoisted tile-invariant read offsets (chunk = k16*2 + hi, XOR row&7 = x7)
    int co[4];
    #pragma unroll
    for (int ks = 0; ks < 4; ++ks) co[ks] = (((ks * 2 + hi) ^ x7) * 8);
    const int krow = l31 * 64;

    auto stage = [&](int buf, int kv0) {
        async_lds16(&Kg[base + (size_t)(kv0 + r0) * 1024 + csw * 8],      &Ks[buf][tid * 8]);
        async_lds16(&Kg[base + (size_t)(kv0 + 32 + r0) * 1024 + csw * 8], &Ks[buf][2048 + tid * 8]);
        async_lds16(&Vt[vbase + (size_t)r0 * 8192 + kv0 + csw * 8],        &Vs[buf][tid * 8]);
        async_lds16(&Vt[vbase + (size_t)(r0 + 32) * 8192 + kv0 + csw * 8], &Vs[buf][2048 + tid * 8]);
    };

    // exp2 + pack + permlane transpose: st (D: col q=l31, 16 kv rows) -> 2 A-fragments
    auto procP = [&](const floatx16& st, bf16x8& paA, bf16x8& paB) {
        float e[16];
        #pragma unroll
        for (int i = 0; i < 16; ++i) e[i] = __builtin_amdgcn_exp2f(st[i]);
        racc += ((e[0]+e[1])+(e[2]+e[3])) + ((e[4]+e[5])+(e[6]+e[7]))
              + ((e[8]+e[9])+(e[10]+e[11])) + ((e[12]+e[13])+(e[14]+e[15]));
        const int w0 = (int)pk2(e[0],  e[1]);
        const int w1 = (int)pk2(e[2],  e[3]);
        const int w2 = (int)pk2(e[4],  e[5]);
        const int w3 = (int)pk2(e[6],  e[7]);
        const int w4 = (int)pk2(e[8],  e[9]);
        const int w5 = (int)pk2(e[10], e[11]);
        const int w6 = (int)pk2(e[12], e[13]);
        const int w7 = (int)pk2(e[14], e[15]);
        // swap: a' = [a.lo | b.lo], b' = [a.hi | b.hi]
        const int2v a0 = __builtin_amdgcn_permlane32_swap(w0, w2, false, false);
        const int2v a1 = __builtin_amdgcn_permlane32_swap(w1, w3, false, false);
        const int2v a2 = __builtin_amdgcn_permlane32_swap(w4, w6, false, false);
        const int2v a3 = __builtin_amdgcn_permlane32_swap(w5, w7, false, false);
        paA = mk8(a0.x, a1.x, a0.y, a1.y);   // kv k-step lo: lanes<32 k0-7, >=32 k8-15
        paB = mk8(a2.x, a3.x, a2.y, a3.y);   // kv k-step hi
    };

    stage(0, 0);
    for (int t = 0; t < 32; ++t) {
        __syncthreads();
        if (t < 31) stage((t + 1) & 1, (t + 1) * 64);
        const unsigned short* Kc = &Ks[t & 1][0];
        const unsigned short* Vc = &Vs[t & 1][0];

        // ---- S^T = K Q^T : 2 kv-blocks x 4 d-steps of 32x32x16 ----
        floatx16 st0 = Z16, st1 = Z16;
        __builtin_amdgcn_s_setprio(1);
        #pragma unroll
        for (int ks = 0; ks < 4; ++ks) {
            const bf16x8 kf0 = *(const bf16x8*)&Kc[krow + co[ks]];
            const bf16x8 kf1 = *(const bf16x8*)&Kc[2048 + krow + co[ks]];
            st0 = MFMA_32x32x16(kf0, qf[ks], st0);
            st1 = MFMA_32x32x16(kf1, qf[ks], st1);
        }
        __builtin_amdgcn_s_setprio(0);

        // ---- P = 2^S^T, transpose to A-fragments in registers ----
        bf16x8 pa[4];
        procP(st0, pa[0], pa[1]);   // kv 0-15, 16-31
        procP(st1, pa[2], pa[3]);   // kv 32-47, 48-63

        // ---- O += P V : 4 kv k-steps x 2 d-blocks ----
        __builtin_amdgcn_s_setprio(1);
        #pragma unroll
        for (int f = 0; f < 4; ++f) {
            const bf16x8 v0 = *(const bf16x8*)&Vc[krow + co[f]];
            const bf16x8 v1 = *(const bf16x8*)&Vc[2048 + krow + co[f]];
            o0 = MFMA_32x32x16(pa[f], v0, o0);
            o1 = MFMA_32x32x16(pa[f], v1, o1);
        }
        __builtin_amdgcn_s_setprio(0);
    }

    // ---- rowsum: combine lane halves (rows split across hi), transpose via tiny LDS ----
    const int ri = __float_as_int(racc);
    const int2v rsw = __builtin_amdgcn_permlane32_swap(ri, ri, false, false);
    const float total = __int_as_float(rsw.x) + __int_as_float(rsw.y);  // full sum for q=l31
    rsb[wave][l31] = total;   // lanes l and l+32 write same value (benign)
    // same-wave DS ordering; compiler inserts lgkmcnt before dependent reads
    #pragma unroll
    for (int g = 0; g < 4; ++g) {
        const floatx4 rq = *(const floatx4*)&rsb[wave][4 * hi + 8 * g];
        #pragma unroll
        for (int e2 = 0; e2 < 4; ++e2) {
            const float inv = 1.0f / rq[e2];
            const int reg = g * 4 + e2;
            const size_t row = q0 + 8 * g + 4 * hi + e2;
            Y[base + row * 1024 + l31]      = f2b(o0[reg] * inv);
            Y[base + row * 1024 + 32 + l31] = f2b(o1[reg] * inv);
        }
    }
}

extern "C" void kernel_launch(void* const* d_in, const int* in_sizes, int n_in,
                              void* d_out, int out_size, void* d_ws, size_t ws_size,
                              hipStream_t stream)
{
    const float* dec = (const float*)d_in[0];
    const float* enc = (const float*)d_in[1];
    const float* Wq  = (const float*)d_in[2];
    const float* bq  = (const float*)d_in[3];
    const float* Wk  = (const float*)d_in[4];
    const float* bk  = (const float*)d_in[5];
    const float* Wv  = (const float*)d_in[6];
    const float* bv  = (const float*)d_in[7];
    const float* Wp  = (const float*)d_in[8];
    const float* bp  = (const float*)d_in[9];

    const size_t NTOK = 8192, DM = 1024;
    unsigned short* ws = (unsigned short*)d_ws;
    unsigned short* decB = ws;
    unsigned short* encB = decB + NTOK * DM;
    unsigned short* WqB  = encB + NTOK * DM;
    unsigned short* WkB  = WqB + DM * DM;
    unsigned short* WvB  = WkB + DM * DM;
    unsigned short* WpB  = WvB + DM * DM;
    unsigned short* Qb   = WpB + DM * DM;
    unsigned short* Kb   = Qb + NTOK * DM;
    unsigned short* VtG  = Kb + NTOK * DM;           // [1024][8192]
    unsigned short* Yb   = VtG + NTOK * DM;

    const float C_SM = 0.18033688f;   // log2(e) / sqrt(64)

    CvtArgs a;
    a.src[0] = dec; a.src[1] = enc; a.src[2] = Wq; a.src[3] = Wk; a.src[4] = Wv; a.src[5] = Wp;
    a.dst[0] = decB; a.dst[1] = encB; a.dst[2] = WqB; a.dst[3] = WkB; a.dst[4] = WvB; a.dst[5] = WpB;
    a.scale[0] = 1.f; a.scale[1] = 1.f; a.scale[2] = C_SM;
    a.scale[3] = 1.f; a.scale[4] = 1.f; a.scale[5] = 1.f;
    a.n8[0] = a.n8[1] = (int)(NTOK * DM / 8);
    a.n8[2] = a.n8[3] = a.n8[4] = a.n8[5] = (int)(DM * DM / 8);
    convert_kernel<<<dim3(4096, 6), 256, 0, stream>>>(a);

    QKVArgs qa;
    qa.A[0] = decB; qa.A[1] = encB; qa.A[2] = encB;
    qa.B[0] = WqB;  qa.B[1] = WkB;  qa.B[2] = WvB;
    qa.bias[0] = bq; qa.bias[1] = bk; qa.bias[2] = bv;
    qa.bscale[0] = C_SM; qa.bscale[1] = 1.f; qa.bscale[2] = 1.f;
    qa.C[0] = Qb;   qa.C[1] = Kb;   qa.C[2] = VtG;
    gemm_qkv<<<dim3(512, 1, 3), 256, 0, stream>>>(qa);

    attn_kernel<<<dim3(1024), 256, 0, stream>>>(Qb, Kb, VtG, Yb);
    gemm_out<<<dim3(512), 256, 0, stream>>>(Yb, WpB, bp, (float*)d_out, 8192, 1024, 1024);
}

// Round 4
// 323.642 us; speedup vs baseline: 1.1316x; 1.0034x over previous
//
#include <hip/hip_runtime.h>
#include <hip/hip_bf16.h>

typedef __attribute__((ext_vector_type(8))) short bf16x8;   // 8 bf16 in 4 VGPRs
typedef __attribute__((ext_vector_type(4))) float floatx4;
typedef __attribute__((ext_vector_type(16))) float floatx16;
typedef __attribute__((ext_vector_type(2))) int int2v;

#define MFMA_16x16x32(A, B, C) __builtin_amdgcn_mfma_f32_16x16x32_bf16(A, B, C, 0, 0, 0)
#define MFMA_32x32x16(A, B, C) __builtin_amdgcn_mfma_f32_32x32x16_bf16(A, B, C, 0, 0, 0)

__device__ __forceinline__ unsigned short f2b(float f) {
    __hip_bfloat16 h = __float2bfloat16(f);  // RNE
    unsigned short u;
    __builtin_memcpy(&u, &h, 2);
    return u;
}
// pack 2 floats -> 2 bf16 (RNE) in one u32 (v_cvt_pk_bf16_f32 on gfx950)
__device__ __forceinline__ unsigned pk2(float a, float b) {
    __hip_bfloat162 h = __float22bfloat162_rn(float2{a, b});
    unsigned u;
    __builtin_memcpy(&u, &h, 4);
    return u;
}
__device__ __forceinline__ bf16x8 mk8(int a, int b, int c, int d) {
    union { int u[4]; bf16x8 v; } x;
    x.u[0] = a; x.u[1] = b; x.u[2] = c; x.u[3] = d;
    return x.v;
}
__device__ __forceinline__ void async_lds16(const void* g, void* l) {
    __builtin_amdgcn_global_load_lds((__attribute__((address_space(1))) void*)g,
                                     (__attribute__((address_space(3))) void*)l, 16, 0, 0);
}

// ---------------- fp32 -> bf16 bulk convert (with per-tensor scale) ----------------
struct CvtArgs {
    const float* src[6];
    unsigned short* dst[6];
    float scale[6];
    int n8[6];
};
__global__ __launch_bounds__(256) void convert_kernel(CvtArgs a) {
    const int t = blockIdx.y;
    const int i = blockIdx.x * 256 + threadIdx.x;
    if (i >= a.n8[t]) return;
    const float sc = a.scale[t];
    const float4* s = (const float4*)a.src[t];
    const float4 x = s[2 * i], y = s[2 * i + 1];
    bf16x8 v;
    v[0] = (short)f2b(x.x * sc); v[1] = (short)f2b(x.y * sc);
    v[2] = (short)f2b(x.z * sc); v[3] = (short)f2b(x.w * sc);
    v[4] = (short)f2b(y.x * sc); v[5] = (short)f2b(y.y * sc);
    v[6] = (short)f2b(y.z * sc); v[7] = (short)f2b(y.w * sc);
    *(bf16x8*)(a.dst[t] + (size_t)i * 8) = v;
}

// ---------------- fused QKV projection GEMM: 256x128 tile, 8 waves, LDS XOR-swizzle ----
// LDS storage rule: slot(row, cc) holds global chunk g = cc ^ F(row),
// F(row) = (row ^ (row>>2)) & 3. Reads at (row, quad) -> slot row*4 + (quad ^ F(row)):
// per-16-lane phase each bank-group gets exactly 2 rows (proven-free structure)
// vs 8 rows un-swizzled (m98's 1.7e7-conflict pattern).
struct QKVArgs {
    const unsigned short* A[3];
    const unsigned short* B[3];
    const float* bias[3];
    float bscale[3];
    unsigned short* C[3];
};
__global__ __launch_bounds__(512, 2) void gemm_qkv(QKVArgs args) {
    constexpr int M = 8192, N = 1024, K = 1024;
    __shared__ __align__(16) unsigned short As[2][8192];   // 256 x 32
    __shared__ __align__(16) unsigned short Bs[2][4096];   // 128 x 32

    const int z = blockIdx.z;
    const unsigned short* __restrict__ A = args.A[z];
    const unsigned short* __restrict__ B = args.B[z];
    const float* __restrict__ bias = args.bias[z];
    const float bsc = args.bscale[z];
    unsigned short* __restrict__ C = args.C[z];

    const int tid  = threadIdx.x;
    const int wave = tid >> 6;      // 0..7
    const int lane = tid & 63;
    const int l16  = lane & 15;
    const int quad = lane >> 4;
    const int bm = (blockIdx.x & 31) * 256;
    const int bn = (blockIdx.x >> 5) * 128;
    const int wm = (wave >> 1) * 64;
    const int wn = (wave & 1) * 64;

    const int srow = tid >> 2;                                              // 0..127
    const int skb  = (((tid & 3) ^ ((tid >> 2) & 3) ^ ((tid >> 4) & 3)) * 8); // swizzled src chunk
    const int cq   = ((quad ^ (l16 & 3) ^ ((l16 >> 2) & 3)) * 8);             // swizzled read chunk

    floatx4 acc[4][4] = {};

    auto stage = [&](int buf, int k0) {
        async_lds16(A + (size_t)(bm + srow) * K + skb + k0,       &As[buf][tid * 8]);
        async_lds16(A + (size_t)(bm + 128 + srow) * K + skb + k0, &As[buf][4096 + tid * 8]);
        async_lds16(B + (size_t)(bn + srow) * K + skb + k0,       &Bs[buf][tid * 8]);
    };

    stage(0, 0);
    for (int it = 0; it < K / 32; ++it) {
        __syncthreads();
        if (it + 1 < K / 32) stage((it + 1) & 1, (it + 1) * 32);
        const unsigned short* Ac = &As[it & 1][0];
        const unsigned short* Bc = &Bs[it & 1][0];

        bf16x8 af[4], bfr[4];
        #pragma unroll
        for (int i = 0; i < 4; ++i)
            af[i] = *(const bf16x8*)&Ac[(wm + i * 16 + l16) * 32 + cq];
        #pragma unroll
        for (int j = 0; j < 4; ++j)
            bfr[j] = *(const bf16x8*)&Bc[(wn + j * 16 + l16) * 32 + cq];
        #pragma unroll
        for (int i = 0; i < 4; ++i)
            #pragma unroll
            for (int j = 0; j < 4; ++j)
                acc[i][j] = MFMA_16x16x32(af[i], bfr[j], acc[i][j]);
    }

    if (z == 2) {
        __syncthreads();
        unsigned short* Tw = &As[0][0] + wave * (16 * 66);   // 8 waves x 1056 <= 16384 shorts
        #pragma unroll
        for (int j = 0; j < 4; ++j) {
            const float bv = bias[bn + wn + j * 16 + l16] * bsc;
            #pragma unroll
            for (int i = 0; i < 4; ++i)
                #pragma unroll
                for (int r = 0; r < 4; ++r)
                    Tw[l16 * 66 + i * 16 + quad * 4 + r] = f2b(acc[i][j][r] + bv);
            __syncthreads();
            const int c2  = lane >> 2;
            const int tch = lane & 3;
            bf16x8 t0 = *(const bf16x8*)&Tw[c2 * 66 + tch * 16];
            bf16x8 t1 = *(const bf16x8*)&Tw[c2 * 66 + tch * 16 + 8];
            const size_t off = (size_t)(bn + wn + j * 16 + c2) * (size_t)M + (bm + wm + tch * 16);
            *(bf16x8*)&C[off]     = t0;
            *(bf16x8*)&C[off + 8] = t1;
            __syncthreads();
        }
    } else {
        #pragma unroll
        for (int i = 0; i < 4; ++i) {
            const int row = bm + wm + i * 16 + quad * 4;
            #pragma unroll
            for (int j = 0; j < 4; ++j) {
                const int col = bn + wn + j * 16 + l16;
                const float bv = bias[col] * bsc;
                #pragma unroll
                for (int r = 0; r < 4; ++r)
                    C[(size_t)(row + r) * N + col] = f2b(acc[i][j][r] + bv);
            }
        }
    }
}

// ---------------- output projection GEMM: 256x128 tile, 8 waves, swizzled ----------------
__global__ __launch_bounds__(512, 2) void gemm_out(
    const unsigned short* __restrict__ A, const unsigned short* __restrict__ B,
    const float* __restrict__ bias, float* __restrict__ C,
    int M, int N, int K)
{
    __shared__ __align__(16) unsigned short As[2][8192];
    __shared__ __align__(16) unsigned short Bs[2][4096];

    const int tid  = threadIdx.x;
    const int wave = tid >> 6;
    const int lane = tid & 63;
    const int l16  = lane & 15;
    const int quad = lane >> 4;
    const int bm = (blockIdx.x & 31) * 256;
    const int bn = (blockIdx.x >> 5) * 128;
    const int wm = (wave >> 1) * 64;
    const int wn = (wave & 1) * 64;

    const int srow = tid >> 2;
    const int skb  = (((tid & 3) ^ ((tid >> 2) & 3) ^ ((tid >> 4) & 3)) * 8);
    const int cq   = ((quad ^ (l16 & 3) ^ ((l16 >> 2) & 3)) * 8);

    floatx4 acc[4][4] = {};

    auto stage = [&](int buf, int k0) {
        async_lds16(A + (size_t)(bm + srow) * K + skb + k0,       &As[buf][tid * 8]);
        async_lds16(A + (size_t)(bm + 128 + srow) * K + skb + k0, &As[buf][4096 + tid * 8]);
        async_lds16(B + (size_t)(bn + srow) * K + skb + k0,       &Bs[buf][tid * 8]);
    };

    stage(0, 0);
    for (int it = 0; it < K / 32; ++it) {
        __syncthreads();
        if (it + 1 < K / 32) stage((it + 1) & 1, (it + 1) * 32);
        const unsigned short* Ac = &As[it & 1][0];
        const unsigned short* Bc = &Bs[it & 1][0];

        bf16x8 af[4], bfr[4];
        #pragma unroll
        for (int i = 0; i < 4; ++i)
            af[i] = *(const bf16x8*)&Ac[(wm + i * 16 + l16) * 32 + cq];
        #pragma unroll
        for (int j = 0; j < 4; ++j)
            bfr[j] = *(const bf16x8*)&Bc[(wn + j * 16 + l16) * 32 + cq];
        #pragma unroll
        for (int i = 0; i < 4; ++i)
            #pragma unroll
            for (int j = 0; j < 4; ++j)
                acc[i][j] = MFMA_16x16x32(af[i], bfr[j], acc[i][j]);
    }

    #pragma unroll
    for (int i = 0; i < 4; ++i) {
        const int row = bm + wm + i * 16 + quad * 4;
        #pragma unroll
        for (int j = 0; j < 4; ++j) {
            const int col = bn + wn + j * 16 + l16;
            const float bv = bias[col];
            #pragma unroll
            for (int r = 0; r < 4; ++r)
                C[(size_t)(row + r) * N + col] = acc[i][j][r] + bv;
        }
    }
}

// ---------------- flash attention v10: conflict-free frags + matrix-pipe rowsum ----------
// vs v9: (a) chunk swizzle gains ^((row>>4)&1)<<2 so lanes l and l+16 (rows 16 apart)
// hit different bank groups -> kills the 4-cyc/read conflict (8.39M/dispatch);
// (b) rowsum back on the matrix pipe (7% busy) via ones-MFMA, freeing ~60 VALU cyc/tile
// (VALU is the top pipe at 52%) and deleting the rsb LDS transpose entirely.
__global__ __launch_bounds__(256, 4) void attn_kernel(
    const unsigned short* __restrict__ Q, const unsigned short* __restrict__ Kg,
    const unsigned short* __restrict__ Vt, unsigned short* __restrict__ Y)
{
    __shared__ __align__(16) unsigned short Ks[2][4096];   // swizzled [kv(64)][d(64)]
    __shared__ __align__(16) unsigned short Vs[2][4096];   // swizzled [d(64)][kv(64)]

    const int tid  = threadIdx.x;
    const int wave = tid >> 6;      // 0..3
    const int lane = tid & 63;
    const int l31  = lane & 31;
    const int hi   = lane >> 5;     // 0/1
    const int x7   = lane & 7;
    const int h4   = ((lane >> 4) & 1) << 2;   // row>>4 parity of l31, as chunk XOR
    const int bh = blockIdx.x & 63;
    const int qt = blockIdx.x >> 6;
    const int b  = bh >> 4;
    const int h  = bh & 15;
    const int q0 = qt * 128 + wave * 32;
    const size_t base  = ((size_t)b * 2048) * 1024 + (size_t)h * 64;
    const size_t vbase = ((size_t)h * 64) * 8192 + (size_t)b * 2048;

    // Q fragments (B-operand, 32x32x16): qf[ks] = Q[q0 + l31][d = ks*16 + hi*8 .. +8]
    bf16x8 qf[4];
    {
        const size_t qrow = base + (size_t)(q0 + l31) * 1024 + hi * 8;
        #pragma unroll
        for (int ks = 0; ks < 4; ++ks)
            qf[ks] = *(const bf16x8*)&Q[qrow + ks * 16];
    }

    bf16x8 ones;
    #pragma unroll
    for (int e = 0; e < 8; ++e) ones[e] = (short)0x3F80;   // bf16 1.0
    const floatx16 Z16 = {0.f,0.f,0.f,0.f,0.f,0.f,0.f,0.f,
                          0.f,0.f,0.f,0.f,0.f,0.f,0.f,0.f};

    floatx16 o0 = Z16, o1 = Z16;    // O[q rows][d = blk*32 + l31]
    floatx16 rs = Z16;              // rowsum via ones-MFMA; same C-layout as o

    // staging: slot(row, cc) holds global chunk cc ^ (row&7) ^ (((row>>4)&1)<<2)
    const int r0  = tid >> 3;                                         // 0..31
    const int csw = (tid & 7) ^ (r0 & 7) ^ (((tid >> 7) & 1) << 2);   // same for rows r0 and r0+32

    // tile-invariant swizzled read offsets: chunk = ks*2 + hi, XOR (row&7)=x7 and h4
    int co[4];
    #pragma unroll
    for (int ks = 0; ks < 4; ++ks) co[ks] = (((ks * 2 + hi) ^ x7 ^ h4) * 8);
    const int krow = l31 * 64;

    auto stage = [&](int buf, int kv0) {
        async_lds16(&Kg[base + (size_t)(kv0 + r0) * 1024 + csw * 8],      &Ks[buf][tid * 8]);
        async_lds16(&Kg[base + (size_t)(kv0 + 32 + r0) * 1024 + csw * 8], &Ks[buf][2048 + tid * 8]);
        async_lds16(&Vt[vbase + (size_t)r0 * 8192 + kv0 + csw * 8],        &Vs[buf][tid * 8]);
        async_lds16(&Vt[vbase + (size_t)(r0 + 32) * 8192 + kv0 + csw * 8], &Vs[buf][2048 + tid * 8]);
    };

    // exp2 + pack + permlane transpose: st (D: col q=l31, 16 kv rows) -> 2 A-fragments
    auto procP = [&](const floatx16& st, bf16x8& paA, bf16x8& paB) {
        float e[16];
        #pragma unroll
        for (int i = 0; i < 16; ++i) e[i] = __builtin_amdgcn_exp2f(st[i]);
        const int w0 = (int)pk2(e[0],  e[1]);
        const int w1 = (int)pk2(e[2],  e[3]);
        const int w2 = (int)pk2(e[4],  e[5]);
        const int w3 = (int)pk2(e[6],  e[7]);
        const int w4 = (int)pk2(e[8],  e[9]);
        const int w5 = (int)pk2(e[10], e[11]);
        const int w6 = (int)pk2(e[12], e[13]);
        const int w7 = (int)pk2(e[14], e[15]);
        const int2v a0 = __builtin_amdgcn_permlane32_swap(w0, w2, false, false);
        const int2v a1 = __builtin_amdgcn_permlane32_swap(w1, w3, false, false);
        const int2v a2 = __builtin_amdgcn_permlane32_swap(w4, w6, false, false);
        const int2v a3 = __builtin_amdgcn_permlane32_swap(w5, w7, false, false);
        paA = mk8(a0.x, a1.x, a0.y, a1.y);   // kv k-step lo
        paB = mk8(a2.x, a3.x, a2.y, a3.y);   // kv k-step hi
    };

    stage(0, 0);
    for (int t = 0; t < 32; ++t) {
        __syncthreads();
        if (t < 31) stage((t + 1) & 1, (t + 1) * 64);
        const unsigned short* Kc = &Ks[t & 1][0];
        const unsigned short* Vc = &Vs[t & 1][0];

        // ---- S^T = K Q^T : 2 kv-blocks x 4 d-steps of 32x32x16 ----
        floatx16 st0 = Z16, st1 = Z16;
        __builtin_amdgcn_s_setprio(1);
        #pragma unroll
        for (int ks = 0; ks < 4; ++ks) {
            const bf16x8 kf0 = *(const bf16x8*)&Kc[krow + co[ks]];
            const bf16x8 kf1 = *(const bf16x8*)&Kc[2048 + krow + co[ks]];
            st0 = MFMA_32x32x16(kf0, qf[ks], st0);
            st1 = MFMA_32x32x16(kf1, qf[ks], st1);
        }
        __builtin_amdgcn_s_setprio(0);

        // ---- P = 2^S^T, transpose to A-fragments in registers ----
        bf16x8 pa[4];
        procP(st0, pa[0], pa[1]);   // kv 0-15, 16-31
        procP(st1, pa[2], pa[3]);   // kv 32-47, 48-63

        // ---- O += P V ; rowsum += P @ ones (matrix pipe) ----
        __builtin_amdgcn_s_setprio(1);
        #pragma unroll
        for (int f = 0; f < 4; ++f) {
            const bf16x8 v0 = *(const bf16x8*)&Vc[krow + co[f]];
            const bf16x8 v1 = *(const bf16x8*)&Vc[2048 + krow + co[f]];
            o0 = MFMA_32x32x16(pa[f], v0, o0);
            o1 = MFMA_32x32x16(pa[f], v1, o1);
            rs = MFMA_32x32x16(pa[f], ones, rs);
        }
        __builtin_amdgcn_s_setprio(0);
    }

    // finalize: rs C-layout matches o (all cols of rs equal rowsum(q_row)) -> direct
    #pragma unroll
    for (int g = 0; g < 4; ++g) {
        #pragma unroll
        for (int e2 = 0; e2 < 4; ++e2) {
            const int reg = g * 4 + e2;
            const float inv = 1.0f / rs[reg];
            const size_t row = q0 + 8 * g + 4 * hi + e2;
            Y[base + row * 1024 + l31]      = f2b(o0[reg] * inv);
            Y[base + row * 1024 + 32 + l31] = f2b(o1[reg] * inv);
        }
    }
}

extern "C" void kernel_launch(void* const* d_in, const int* in_sizes, int n_in,
                              void* d_out, int out_size, void* d_ws, size_t ws_size,
                              hipStream_t stream)
{
    const float* dec = (const float*)d_in[0];
    const float* enc = (const float*)d_in[1];
    const float* Wq  = (const float*)d_in[2];
    const float* bq  = (const float*)d_in[3];
    const float* Wk  = (const float*)d_in[4];
    const float* bk  = (const float*)d_in[5];
    const float* Wv  = (const float*)d_in[6];
    const float* bv  = (const float*)d_in[7];
    const float* Wp  = (const float*)d_in[8];
    const float* bp  = (const float*)d_in[9];

    const size_t NTOK = 8192, DM = 1024;
    unsigned short* ws = (unsigned short*)d_ws;
    unsigned short* decB = ws;
    unsigned short* encB = decB + NTOK * DM;
    unsigned short* WqB  = encB + NTOK * DM;
    unsigned short* WkB  = WqB + DM * DM;
    unsigned short* WvB  = WkB + DM * DM;
    unsigned short* WpB  = WvB + DM * DM;
    unsigned short* Qb   = WpB + DM * DM;
    unsigned short* Kb   = Qb + NTOK * DM;
    unsigned short* VtG  = Kb + NTOK * DM;           // [1024][8192]
    unsigned short* Yb   = VtG + NTOK * DM;

    const float C_SM = 0.18033688f;   // log2(e) / sqrt(64)

    CvtArgs a;
    a.src[0] = dec; a.src[1] = enc; a.src[2] = Wq; a.src[3] = Wk; a.src[4] = Wv; a.src[5] = Wp;
    a.dst[0] = decB; a.dst[1] = encB; a.dst[2] = WqB; a.dst[3] = WkB; a.dst[4] = WvB; a.dst[5] = WpB;
    a.scale[0] = 1.f; a.scale[1] = 1.f; a.scale[2] = C_SM;
    a.scale[3] = 1.f; a.scale[4] = 1.f; a.scale[5] = 1.f;
    a.n8[0] = a.n8[1] = (int)(NTOK * DM / 8);
    a.n8[2] = a.n8[3] = a.n8[4] = a.n8[5] = (int)(DM * DM / 8);
    convert_kernel<<<dim3(4096, 6), 256, 0, stream>>>(a);

    QKVArgs qa;
    qa.A[0] = decB; qa.A[1] = encB; qa.A[2] = encB;
    qa.B[0] = WqB;  qa.B[1] = WkB;  qa.B[2] = WvB;
    qa.bias[0] = bq; qa.bias[1] = bk; qa.bias[2] = bv;
    qa.bscale[0] = C_SM; qa.bscale[1] = 1.f; qa.bscale[2] = 1.f;
    qa.C[0] = Qb;   qa.C[1] = Kb;   qa.C[2] = VtG;
    gemm_qkv<<<dim3(256, 1, 3), 512, 0, stream>>>(qa);

    attn_kernel<<<dim3(1024), 256, 0, stream>>>(Qb, Kb, VtG, Yb);
    gemm_out<<<dim3(256), 512, 0, stream>>>(Yb, WpB, bp, (float*)d_out, 8192, 1024, 1024);
}

// Round 5
// 319.649 us; speedup vs baseline: 1.1458x; 1.0125x over previous
//
#include <hip/hip_runtime.h>
#include <hip/hip_bf16.h>

typedef __attribute__((ext_vector_type(8))) short bf16x8;   // 8 bf16 in 4 VGPRs
typedef __attribute__((ext_vector_type(4))) float floatx4;
typedef __attribute__((ext_vector_type(16))) float floatx16;
typedef __attribute__((ext_vector_type(2))) int int2v;

#define MFMA_16x16x32(A, B, C) __builtin_amdgcn_mfma_f32_16x16x32_bf16(A, B, C, 0, 0, 0)
#define MFMA_32x32x16(A, B, C) __builtin_amdgcn_mfma_f32_32x32x16_bf16(A, B, C, 0, 0, 0)

__device__ __forceinline__ unsigned short f2b(float f) {
    __hip_bfloat16 h = __float2bfloat16(f);  // RNE
    unsigned short u;
    __builtin_memcpy(&u, &h, 2);
    return u;
}
// pack 2 floats -> 2 bf16 (RNE) in one u32 (v_cvt_pk_bf16_f32 on gfx950)
__device__ __forceinline__ unsigned pk2(float a, float b) {
    __hip_bfloat162 h = __float22bfloat162_rn(float2{a, b});
    unsigned u;
    __builtin_memcpy(&u, &h, 4);
    return u;
}
__device__ __forceinline__ bf16x8 mk8(int a, int b, int c, int d) {
    union { int u[4]; bf16x8 v; } x;
    x.u[0] = a; x.u[1] = b; x.u[2] = c; x.u[3] = d;
    return x.v;
}
__device__ __forceinline__ void async_lds16(const void* g, void* l) {
    __builtin_amdgcn_global_load_lds((__attribute__((address_space(1))) void*)g,
                                     (__attribute__((address_space(3))) void*)l, 16, 0, 0);
}

// ---------------- fp32 -> bf16 bulk convert (with per-tensor scale) ----------------
struct CvtArgs {
    const float* src[6];
    unsigned short* dst[6];
    float scale[6];
    int n8[6];
};
__global__ __launch_bounds__(256) void convert_kernel(CvtArgs a) {
    const int t = blockIdx.y;
    const int i = blockIdx.x * 256 + threadIdx.x;
    if (i >= a.n8[t]) return;
    const float sc = a.scale[t];
    const float4* s = (const float4*)a.src[t];
    const float4 x = s[2 * i], y = s[2 * i + 1];
    bf16x8 v;
    v[0] = (short)f2b(x.x * sc); v[1] = (short)f2b(x.y * sc);
    v[2] = (short)f2b(x.z * sc); v[3] = (short)f2b(x.w * sc);
    v[4] = (short)f2b(y.x * sc); v[5] = (short)f2b(y.y * sc);
    v[6] = (short)f2b(y.z * sc); v[7] = (short)f2b(y.w * sc);
    *(bf16x8*)(a.dst[t] + (size_t)i * 8) = v;
}

// ---------------- fused QKV projection GEMM: 128x128, 4 waves, 4 blocks/CU ----------------
// Tile reverted to the measured-best 128^2 (m105: 912 vs 792 TF for 256-tile at this
// structure). __launch_bounds__(256,4) caps VGPR at 128 (demand ~116) -> 4 blocks/CU
// = 16 waves/CU for barrier-drain hiding. LDS read swizzle: slot s of row r holds
// chunk s ^ F(r), F(r) = (r ^ (r>>2)) & 3.
// z==2 writes C^T directly as packed b64 (4 acc values are address-consecutive in C^T),
// deleting the 12-barrier LDS transpose epilogue.
struct QKVArgs {
    const unsigned short* A[3];
    const unsigned short* B[3];
    const float* bias[3];
    float bscale[3];
    unsigned short* C[3];
};
__global__ __launch_bounds__(256, 4) void gemm_qkv(QKVArgs args) {
    constexpr int M = 8192, N = 1024, K = 1024;
    __shared__ __align__(16) unsigned short As[2][4096];   // 128 x 32
    __shared__ __align__(16) unsigned short Bs[2][4096];   // 128 x 32

    const int z = blockIdx.z;
    const unsigned short* __restrict__ A = args.A[z];
    const unsigned short* __restrict__ B = args.B[z];
    const float* __restrict__ bias = args.bias[z];
    const float bsc = args.bscale[z];
    unsigned short* __restrict__ C = args.C[z];

    const int tid  = threadIdx.x;
    const int wave = tid >> 6;      // 0..3
    const int lane = tid & 63;
    const int l16  = lane & 15;
    const int quad = lane >> 4;
    const int bm = (blockIdx.x & 63) * 128;
    const int bn = (blockIdx.x >> 6) * 128;
    const int wm = (wave >> 1) * 64;
    const int wn = (wave & 1) * 64;

    const int srow = tid >> 2;                                                // 0..63
    const int skb  = (((tid & 3) ^ ((tid >> 2) & 3) ^ ((tid >> 4) & 3)) * 8); // chunk ^ F(row)
    const int cq   = ((quad ^ (l16 & 3) ^ ((l16 >> 2) & 3)) * 8);             // read: quad ^ F(row)

    floatx4 acc[4][4] = {};

    auto stage = [&](int buf, int k0) {
        async_lds16(A + (size_t)(bm + srow) * K + skb + k0,      &As[buf][tid * 8]);
        async_lds16(A + (size_t)(bm + 64 + srow) * K + skb + k0, &As[buf][2048 + tid * 8]);
        async_lds16(B + (size_t)(bn + srow) * K + skb + k0,      &Bs[buf][tid * 8]);
        async_lds16(B + (size_t)(bn + 64 + srow) * K + skb + k0, &Bs[buf][2048 + tid * 8]);
    };

    stage(0, 0);
    for (int it = 0; it < K / 32; ++it) {
        __syncthreads();
        if (it + 1 < K / 32) stage((it + 1) & 1, (it + 1) * 32);
        const unsigned short* Ac = &As[it & 1][0];
        const unsigned short* Bc = &Bs[it & 1][0];

        bf16x8 af[4], bfr[4];
        #pragma unroll
        for (int i = 0; i < 4; ++i)
            af[i] = *(const bf16x8*)&Ac[(wm + i * 16 + l16) * 32 + cq];
        #pragma unroll
        for (int j = 0; j < 4; ++j)
            bfr[j] = *(const bf16x8*)&Bc[(wn + j * 16 + l16) * 32 + cq];
        #pragma unroll
        for (int i = 0; i < 4; ++i)
            #pragma unroll
            for (int j = 0; j < 4; ++j)
                acc[i][j] = MFMA_16x16x32(af[i], bfr[j], acc[i][j]);
    }

    if (z == 2) {
        // direct C^T b64 stores: C^T[col][row], lane's 4 acc values are consecutive rows
        #pragma unroll
        for (int j = 0; j < 4; ++j) {
            const int col = bn + wn + j * 16 + l16;
            const float bv = bias[col] * bsc;
            #pragma unroll
            for (int i = 0; i < 4; ++i) {
                uint2 w;
                w.x = pk2(acc[i][j][0] + bv, acc[i][j][1] + bv);
                w.y = pk2(acc[i][j][2] + bv, acc[i][j][3] + bv);
                const size_t off = (size_t)col * (size_t)M + (bm + wm + i * 16 + quad * 4);
                *(uint2*)&C[off] = w;
            }
        }
    } else {
        #pragma unroll
        for (int i = 0; i < 4; ++i) {
            const int row = bm + wm + i * 16 + quad * 4;
            #pragma unroll
            for (int j = 0; j < 4; ++j) {
                const int col = bn + wn + j * 16 + l16;
                const float bv = bias[col] * bsc;
                #pragma unroll
                for (int r = 0; r < 4; ++r)
                    C[(size_t)(row + r) * N + col] = f2b(acc[i][j][r] + bv);
            }
        }
    }
}

// ---------------- output projection GEMM: 128x128, 4 waves, 4 blocks/CU ----------------
__global__ __launch_bounds__(256, 4) void gemm_out(
    const unsigned short* __restrict__ A, const unsigned short* __restrict__ B,
    const float* __restrict__ bias, float* __restrict__ C,
    int M, int N, int K)
{
    __shared__ __align__(16) unsigned short As[2][4096];
    __shared__ __align__(16) unsigned short Bs[2][4096];

    const int tid  = threadIdx.x;
    const int wave = tid >> 6;
    const int lane = tid & 63;
    const int l16  = lane & 15;
    const int quad = lane >> 4;
    const int bm = (blockIdx.x & 63) * 128;
    const int bn = (blockIdx.x >> 6) * 128;
    const int wm = (wave >> 1) * 64;
    const int wn = (wave & 1) * 64;

    const int srow = tid >> 2;
    const int skb  = (((tid & 3) ^ ((tid >> 2) & 3) ^ ((tid >> 4) & 3)) * 8);
    const int cq   = ((quad ^ (l16 & 3) ^ ((l16 >> 2) & 3)) * 8);

    floatx4 acc[4][4] = {};

    auto stage = [&](int buf, int k0) {
        async_lds16(A + (size_t)(bm + srow) * K + skb + k0,      &As[buf][tid * 8]);
        async_lds16(A + (size_t)(bm + 64 + srow) * K + skb + k0, &As[buf][2048 + tid * 8]);
        async_lds16(B + (size_t)(bn + srow) * K + skb + k0,      &Bs[buf][tid * 8]);
        async_lds16(B + (size_t)(bn + 64 + srow) * K + skb + k0, &Bs[buf][2048 + tid * 8]);
    };

    stage(0, 0);
    for (int it = 0; it < K / 32; ++it) {
        __syncthreads();
        if (it + 1 < K / 32) stage((it + 1) & 1, (it + 1) * 32);
        const unsigned short* Ac = &As[it & 1][0];
        const unsigned short* Bc = &Bs[it & 1][0];

        bf16x8 af[4], bfr[4];
        #pragma unroll
        for (int i = 0; i < 4; ++i)
            af[i] = *(const bf16x8*)&Ac[(wm + i * 16 + l16) * 32 + cq];
        #pragma unroll
        for (int j = 0; j < 4; ++j)
            bfr[j] = *(const bf16x8*)&Bc[(wn + j * 16 + l16) * 32 + cq];
        #pragma unroll
        for (int i = 0; i < 4; ++i)
            #pragma unroll
            for (int j = 0; j < 4; ++j)
                acc[i][j] = MFMA_16x16x32(af[i], bfr[j], acc[i][j]);
    }

    #pragma unroll
    for (int i = 0; i < 4; ++i) {
        const int row = bm + wm + i * 16 + quad * 4;
        #pragma unroll
        for (int j = 0; j < 4; ++j) {
            const int col = bn + wn + j * 16 + l16;
            const float bv = bias[col];
            #pragma unroll
            for (int r = 0; r < 4; ++r)
                C[(size_t)(row + r) * N + col] = acc[i][j][r] + bv;
        }
    }
}

// ---------------- flash attention v10 (unchanged control): 32x32 MFMA, in-reg P ----------
__global__ __launch_bounds__(256, 4) void attn_kernel(
    const unsigned short* __restrict__ Q, const unsigned short* __restrict__ Kg,
    const unsigned short* __restrict__ Vt, unsigned short* __restrict__ Y)
{
    __shared__ __align__(16) unsigned short Ks[2][4096];   // swizzled [kv(64)][d(64)]
    __shared__ __align__(16) unsigned short Vs[2][4096];   // swizzled [d(64)][kv(64)]

    const int tid  = threadIdx.x;
    const int wave = tid >> 6;      // 0..3
    const int lane = tid & 63;
    const int l31  = lane & 31;
    const int hi   = lane >> 5;     // 0/1
    const int x7   = lane & 7;
    const int h4   = ((lane >> 4) & 1) << 2;
    const int bh = blockIdx.x & 63;
    const int qt = blockIdx.x >> 6;
    const int b  = bh >> 4;
    const int h  = bh & 15;
    const int q0 = qt * 128 + wave * 32;
    const size_t base  = ((size_t)b * 2048) * 1024 + (size_t)h * 64;
    const size_t vbase = ((size_t)h * 64) * 8192 + (size_t)b * 2048;

    bf16x8 qf[4];
    {
        const size_t qrow = base + (size_t)(q0 + l31) * 1024 + hi * 8;
        #pragma unroll
        for (int ks = 0; ks < 4; ++ks)
            qf[ks] = *(const bf16x8*)&Q[qrow + ks * 16];
    }

    bf16x8 ones;
    #pragma unroll
    for (int e = 0; e < 8; ++e) ones[e] = (short)0x3F80;   // bf16 1.0
    const floatx16 Z16 = {0.f,0.f,0.f,0.f,0.f,0.f,0.f,0.f,
                          0.f,0.f,0.f,0.f,0.f,0.f,0.f,0.f};

    floatx16 o0 = Z16, o1 = Z16;
    floatx16 rs = Z16;

    const int r0  = tid >> 3;
    const int csw = (tid & 7) ^ (r0 & 7) ^ (((tid >> 7) & 1) << 2);

    int co[4];
    #pragma unroll
    for (int ks = 0; ks < 4; ++ks) co[ks] = (((ks * 2 + hi) ^ x7 ^ h4) * 8);
    const int krow = l31 * 64;

    auto stage = [&](int buf, int kv0) {
        async_lds16(&Kg[base + (size_t)(kv0 + r0) * 1024 + csw * 8],      &Ks[buf][tid * 8]);
        async_lds16(&Kg[base + (size_t)(kv0 + 32 + r0) * 1024 + csw * 8], &Ks[buf][2048 + tid * 8]);
        async_lds16(&Vt[vbase + (size_t)r0 * 8192 + kv0 + csw * 8],        &Vs[buf][tid * 8]);
        async_lds16(&Vt[vbase + (size_t)(r0 + 32) * 8192 + kv0 + csw * 8], &Vs[buf][2048 + tid * 8]);
    };

    auto procP = [&](const floatx16& st, bf16x8& paA, bf16x8& paB) {
        float e[16];
        #pragma unroll
        for (int i = 0; i < 16; ++i) e[i] = __builtin_amdgcn_exp2f(st[i]);
        const int w0 = (int)pk2(e[0],  e[1]);
        const int w1 = (int)pk2(e[2],  e[3]);
        const int w2 = (int)pk2(e[4],  e[5]);
        const int w3 = (int)pk2(e[6],  e[7]);
        const int w4 = (int)pk2(e[8],  e[9]);
        const int w5 = (int)pk2(e[10], e[11]);
        const int w6 = (int)pk2(e[12], e[13]);
        const int w7 = (int)pk2(e[14], e[15]);
        const int2v a0 = __builtin_amdgcn_permlane32_swap(w0, w2, false, false);
        const int2v a1 = __builtin_amdgcn_permlane32_swap(w1, w3, false, false);
        const int2v a2 = __builtin_amdgcn_permlane32_swap(w4, w6, false, false);
        const int2v a3 = __builtin_amdgcn_permlane32_swap(w5, w7, false, false);
        paA = mk8(a0.x, a1.x, a0.y, a1.y);
        paB = mk8(a2.x, a3.x, a2.y, a3.y);
    };

    stage(0, 0);
    for (int t = 0; t < 32; ++t) {
        __syncthreads();
        if (t < 31) stage((t + 1) & 1, (t + 1) * 64);
        const unsigned short* Kc = &Ks[t & 1][0];
        const unsigned short* Vc = &Vs[t & 1][0];

        floatx16 st0 = Z16, st1 = Z16;
        __builtin_amdgcn_s_setprio(1);
        #pragma unroll
        for (int ks = 0; ks < 4; ++ks) {
            const bf16x8 kf0 = *(const bf16x8*)&Kc[krow + co[ks]];
            const bf16x8 kf1 = *(const bf16x8*)&Kc[2048 + krow + co[ks]];
            st0 = MFMA_32x32x16(kf0, qf[ks], st0);
            st1 = MFMA_32x32x16(kf1, qf[ks], st1);
        }
        __builtin_amdgcn_s_setprio(0);

        bf16x8 pa[4];
        procP(st0, pa[0], pa[1]);
        procP(st1, pa[2], pa[3]);

        __builtin_amdgcn_s_setprio(1);
        #pragma unroll
        for (int f = 0; f < 4; ++f) {
            const bf16x8 v0 = *(const bf16x8*)&Vc[krow + co[f]];
            const bf16x8 v1 = *(const bf16x8*)&Vc[2048 + krow + co[f]];
            o0 = MFMA_32x32x16(pa[f], v0, o0);
            o1 = MFMA_32x32x16(pa[f], v1, o1);
            rs = MFMA_32x32x16(pa[f], ones, rs);
        }
        __builtin_amdgcn_s_setprio(0);
    }

    #pragma unroll
    for (int g = 0; g < 4; ++g) {
        #pragma unroll
        for (int e2 = 0; e2 < 4; ++e2) {
            const int reg = g * 4 + e2;
            const float inv = 1.0f / rs[reg];
            const size_t row = q0 + 8 * g + 4 * hi + e2;
            Y[base + row * 1024 + l31]      = f2b(o0[reg] * inv);
            Y[base + row * 1024 + 32 + l31] = f2b(o1[reg] * inv);
        }
    }
}

extern "C" void kernel_launch(void* const* d_in, const int* in_sizes, int n_in,
                              void* d_out, int out_size, void* d_ws, size_t ws_size,
                              hipStream_t stream)
{
    const float* dec = (const float*)d_in[0];
    const float* enc = (const float*)d_in[1];
    const float* Wq  = (const float*)d_in[2];
    const float* bq  = (const float*)d_in[3];
    const float* Wk  = (const float*)d_in[4];
    const float* bk  = (const float*)d_in[5];
    const float* Wv  = (const float*)d_in[6];
    const float* bv  = (const float*)d_in[7];
    const float* Wp  = (const float*)d_in[8];
    const float* bp  = (const float*)d_in[9];

    const size_t NTOK = 8192, DM = 1024;
    unsigned short* ws = (unsigned short*)d_ws;
    unsigned short* decB = ws;
    unsigned short* encB = decB + NTOK * DM;
    unsigned short* WqB  = encB + NTOK * DM;
    unsigned short* WkB  = WqB + DM * DM;
    unsigned short* WvB  = WkB + DM * DM;
    unsigned short* WpB  = WvB + DM * DM;
    unsigned short* Qb   = WpB + DM * DM;
    unsigned short* Kb   = Qb + NTOK * DM;
    unsigned short* VtG  = Kb + NTOK * DM;           // [1024][8192]
    unsigned short* Yb   = VtG + NTOK * DM;

    const float C_SM = 0.18033688f;   // log2(e) / sqrt(64)

    CvtArgs a;
    a.src[0] = dec; a.src[1] = enc; a.src[2] = Wq; a.src[3] = Wk; a.src[4] = Wv; a.src[5] = Wp;
    a.dst[0] = decB; a.dst[1] = encB; a.dst[2] = WqB; a.dst[3] = WkB; a.dst[4] = WvB; a.dst[5] = WpB;
    a.scale[0] = 1.f; a.scale[1] = 1.f; a.scale[2] = C_SM;
    a.scale[3] = 1.f; a.scale[4] = 1.f; a.scale[5] = 1.f;
    a.n8[0] = a.n8[1] = (int)(NTOK * DM / 8);
    a.n8[2] = a.n8[3] = a.n8[4] = a.n8[5] = (int)(DM * DM / 8);
    convert_kernel<<<dim3(4096, 6), 256, 0, stream>>>(a);

    QKVArgs qa;
    qa.A[0] = decB; qa.A[1] = encB; qa.A[2] = encB;
    qa.B[0] = WqB;  qa.B[1] = WkB;  qa.B[2] = WvB;
    qa.bias[0] = bq; qa.bias[1] = bk; qa.bias[2] = bv;
    qa.bscale[0] = C_SM; qa.bscale[1] = 1.f; qa.bscale[2] = 1.f;
    qa.C[0] = Qb;   qa.C[1] = Kb;   qa.C[2] = VtG;
    gemm_qkv<<<dim3(512, 1, 3), 256, 0, stream>>>(qa);

    attn_kernel<<<dim3(1024), 256, 0, stream>>>(Qb, Kb, VtG, Yb);
    gemm_out<<<dim3(512), 256, 0, stream>>>(Yb, WpB, bp, (float*)d_out, 8192, 1024, 1024);
}